// Round 4
// baseline (270.547 us; speedup 1.0000x reference)
//
#include <hip/hip_runtime.h>

typedef unsigned short u16;
typedef __attribute__((ext_vector_type(8))) _Float16 f16x8;
typedef __attribute__((ext_vector_type(2))) _Float16 f16x2;
typedef __attribute__((ext_vector_type(4))) float f32x4;

#define DEV static __device__ __forceinline__

DEV float bf2f(u16 h){ unsigned u = ((unsigned)h) << 16; return __builtin_bit_cast(float, u); }
DEV u16 f2bf(float f){ unsigned u = __builtin_bit_cast(unsigned, f); u += 0x7FFFu + ((u >> 16) & 1u); return (u16)(u >> 16); }
DEV u16 f2h(float f){ _Float16 h = (_Float16)f; return __builtin_bit_cast(u16, h); }
DEV float h2f(u16 h){ return (float)__builtin_bit_cast(_Float16, h); }

DEV f32x4 mfma16(f16x8 a, f16x8 b, f32x4 c){
  return __builtin_amdgcn_mfma_f32_16x16x32_f16(a, b, c, 0, 0, 0);
}

// relu(S1+R1) on 8 packed halves: 4x v_pk_add_f16 + 4x v_pk_max_f16.
DEV f16x8 build_frag(uint4 s, uint4 r){
  f16x8 a = __builtin_bit_cast(f16x8, s);
  f16x8 b = __builtin_bit_cast(f16x8, r);
  f16x8 v = a + b;
  const f16x8 z = {0,0,0,0,0,0,0,0};
  return __builtin_elementwise_max(v, z);
}

// Sizes: B=64, N=64, F=64, H=256, O=64, T=4, E=4032
// ws layout (bytes): FLAG@0 | W1T@256 | W2T@262400 | OW1T@393472 | OW2T@459008
//  | OW3T@590080 | B1@622848 | B2@624896 | OB1@625408 | OB2@625920 | OB3@626432
//  | Xc@626688 | RTc@1150976 | S1@3215360 | R1@11603968 | AGG(f32)@19992576
#define OFF_W1T  256
#define OFF_W2T  262400
#define OFF_OW1T 393472
#define OFF_OW2T 459008
#define OFF_OW3T 590080
#define OFF_B1   622848
#define OFF_B2   624896
#define OFF_OB1  625408
#define OFF_OB2  625920
#define OFF_OB3  626432
#define OFF_XC   626688
#define OFF_RTC  1150976
#define OFF_S1   3215360
#define OFF_R1   11603968
#define OFF_AGG  19992576

// ---------------- K-1: dtype sniff ----------------
__global__ void k_sniff(const u16* __restrict__ x, int* __restrict__ flag){
  int l = threadIdx.x;
  u16 u = x[2 * l];
  int e = (u >> 7) & 0xFF;
  int ok = (e >= 103 && e <= 143) ? 1 : 0;
  unsigned long long m = __ballot(ok);
  if(l == 0) *flag = (__builtin_popcountll(m) >= 40) ? 1 : 0;  // 1 = bf16 I/O
}

DEV float ldin(const void* p, int i, int isbf){
  return isbf ? bf2f(((const u16*)p)[i]) : ((const float*)p)[i];
}

// ---------------- K0a: tiled transpose+convert for the 5 weight matrices ----------------
// src [G][R][C] -> dst [G][C][R], 32x32 LDS tiles, coalesced read+write.
__global__ __launch_bounds__(256) void k_tr(const void* __restrict__ w1, const void* __restrict__ w2,
    const void* __restrict__ ow1, const void* __restrict__ ow2, const void* __restrict__ ow3,
    char* __restrict__ ws){
  const int isbf = *(const int*)ws;
  __shared__ float tile[32][33];
  int bid = blockIdx.x, tid = threadIdx.x;
  const void* src; u16* dst; int R, C, off, r0, c0;
  if(bid < 128){ int g = bid >> 5, tt = bid & 31;
    src = w1; dst = (u16*)(ws + OFF_W1T); R = 128; C = 256; off = g * 32768;
    r0 = (tt >> 3) << 5; c0 = (tt & 7) << 5;
  } else if(bid < 192){ int bb = bid - 128; int g = bb >> 4, tt = bb & 15;
    src = w2; dst = (u16*)(ws + OFF_W2T); R = 256; C = 64; off = g * 16384;
    r0 = (tt >> 1) << 5; c0 = (tt & 1) << 5;
  } else if(bid < 224){ int bb = bid - 192;
    src = ow1; dst = (u16*)(ws + OFF_OW1T); R = 128; C = 256; off = 0;
    r0 = (bb >> 3) << 5; c0 = (bb & 7) << 5;
  } else if(bid < 288){ int bb = bid - 224;
    src = ow2; dst = (u16*)(ws + OFF_OW2T); R = 256; C = 256; off = 0;
    r0 = (bb >> 3) << 5; c0 = (bb & 7) << 5;
  } else { int bb = bid - 288;
    src = ow3; dst = (u16*)(ws + OFF_OW3T); R = 256; C = 64; off = 0;
    r0 = (bb >> 1) << 5; c0 = (bb & 1) << 5;
  }
  int tx = tid & 31, ty = tid >> 5;
  #pragma unroll
  for(int p = 0; p < 4; ++p){
    int r = ty + p * 8;
    tile[r][tx] = ldin(src, off + (r0 + r) * C + c0 + tx, isbf);
  }
  __syncthreads();
  #pragma unroll
  for(int p = 0; p < 4; ++p){
    int c = ty + p * 8;
    dst[off + (c0 + c) * R + r0 + tx] = f2h(tile[tx][c]);
  }
}

// ---------------- K0b: coalesced elementwise converts (x, rel_type, biases) ----------------
__global__ __launch_bounds__(256) void k_cvt2(const void* __restrict__ x, const void* __restrict__ rt,
    const void* __restrict__ b1, const void* __restrict__ b2,
    const void* __restrict__ ob1, const void* __restrict__ ob2, const void* __restrict__ ob3,
    char* __restrict__ ws){
  const int isbf = *(const int*)ws;
  int n = blockIdx.x * 256 + threadIdx.x;
  if(n < 262144){ ((u16*)(ws+OFF_XC))[n] = f2h(ldin(x, n, isbf)); return; }
  n -= 262144;
  if(n < 1032192){ ((u16*)(ws+OFF_RTC))[n] = f2h(ldin(rt, n, isbf)); return; }
  n -= 1032192;
  if(n < 1024){ ((u16*)(ws+OFF_B1))[n] = f2h(ldin(b1, n, isbf)); return; }
  n -= 1024;
  if(n < 256){ ((u16*)(ws+OFF_B2))[n] = f2h(ldin(b2, n, isbf)); return; }
  n -= 256;
  if(n < 256){ ((u16*)(ws+OFF_OB1))[n] = f2h(ldin(ob1, n, isbf)); return; }
  n -= 256;
  if(n < 256){ ((u16*)(ws+OFF_OB2))[n] = f2h(ldin(ob2, n, isbf)); return; }
  n -= 256;
  if(n < 64){ ((u16*)(ws+OFF_OB3))[n] = f2h(ldin(ob3, n, isbf)); return; }
}

// ---------------- K1: S1/R1 = x @ w1-half (+b1 on receiver half) ----------------
__global__ __launch_bounds__(256) void k_s1r1(const u16* __restrict__ Xc, const u16* __restrict__ W1T,
    const u16* __restrict__ B1c, u16* __restrict__ S1, u16* __restrict__ R1){
  __shared__ __align__(16) u16 sX[64][72];
  __shared__ __align__(16) u16 sW[256][72];
  const int tid = threadIdx.x, bid = blockIdx.x;
  const int b = bid & 63, th = bid >> 6, t = th >> 1, half = th & 1;
  {
    const uint4* src = (const uint4*)(Xc + b*4096);
    #pragma unroll
    for(int it=0; it<2; ++it){
      int c = tid + it*256; int row = c >> 3, col = (c & 7) * 8;
      *(uint4*)&sX[row][col] = src[c];
    }
    const u16* base = W1T + t*32768 + half*64;
    #pragma unroll
    for(int it=0; it<8; ++it){
      int c = tid + it*256; int h = c >> 3, kc = (c & 7) * 8;
      *(uint4*)&sW[h][kc] = *(const uint4*)(base + h*128 + kc);
    }
  }
  __syncthreads();
  const int wv = tid >> 6, l = tid & 63, ml = l & 15, q = l >> 4;
  const f32x4 z = {0.f,0.f,0.f,0.f};
  f32x4 acc[4][4];
  #pragma unroll
  for(int mt=0;mt<4;++mt){ acc[mt][0]=z; acc[mt][1]=z; acc[mt][2]=z; acc[mt][3]=z; }
  #pragma unroll
  for(int ks=0; ks<2; ++ks){
    const int kb = ks*32 + q*8;
    f16x8 af[4], bff[4];
    #pragma unroll
    for(int mt=0;mt<4;++mt) af[mt] = *(const f16x8*)&sX[mt*16 + ml][kb];
    #pragma unroll
    for(int nt=0;nt<4;++nt) bff[nt] = *(const f16x8*)&sW[wv*64 + nt*16 + ml][kb];
    #pragma unroll
    for(int mt=0;mt<4;++mt)
      #pragma unroll
      for(int nt=0;nt<4;++nt)
        acc[mt][nt] = mfma16(af[mt], bff[nt], acc[mt][nt]);
  }
  u16* dst = (half ? R1 : S1) + (t*64 + b)*16384;
  #pragma unroll
  for(int nt=0;nt<4;++nt){
    const int h = wv*64 + nt*16 + ml;
    const float bias = half ? h2f(B1c[t*256 + h]) : 0.0f;
    #pragma unroll
    for(int mt=0;mt<4;++mt)
      #pragma unroll
      for(int r=0;r<4;++r){
        int irow = mt*16 + q*4 + r;
        dst[irow*256 + h] = f2h(acc[mt][nt][r] + bias);
      }
  }
}

// ---------------- K2: per-edge layer-2 + weighted receiver aggregation ----------------
// R4 restructure: 512-thread block (8 waves = 2 waves/SIMD), wave = (t, nh)
// where nh picks 32 of the 64 output cols. Rationale (R0-R3 counters): at
// 1 wave/SIMD ~50% of cycles were pure exposed latency (MfmaUtil 23 +
// VALUBusy 34, both pipes idle otherwise); the old tiling's ~400-reg live
// set could never fit 2 waves. Halving bfr/acc per wave and moving the
// 16x-reused S1 tile to LDS cuts the live set to ~220 regs <= 256, so a
// 512 block forcibly fits 2 waves/SIMD. Price: frag-build VALU duplicated
// across the nh pair + 32 ds_read_b128/jj/wave (LDS has 10x headroom).
// sS1 pad = 264 halves/row: byte addr (row*528 + 16q) -> bank group
// 4*((ml+q)&7): 8 lanes per 4-bank cluster = the b128 minimum, no conflicts.
__global__ __launch_bounds__(512) void k_edge(const u16* __restrict__ RTc, const u16* __restrict__ W2T,
    const u16* __restrict__ B2c, const u16* __restrict__ S1, const u16* __restrict__ R1,
    float* __restrict__ AGG){
  __shared__ __align__(16) u16 sS1[4][64][264];
  __shared__ float sRTa[4][16][64];
  __shared__ float sAggB[1024];
  const int tid = threadIdx.x;
  const int w = tid >> 6, l = tid & 63, ml = l & 15, q = l >> 4;
  const int t = w >> 1, nh = w & 1;
  const int b = blockIdx.x >> 2, j0 = (blockIdx.x & 3) * 16;
  #pragma unroll
  for(int it=0; it<2; ++it) sAggB[it*512 + tid] = 0.0f;
  // stage all 4 S1[t][b] tiles (128 KB) into LDS, coalesced uint4
  #pragma unroll
  for(int tt=0; tt<4; ++tt){
    const uint4* src = (const uint4*)(S1 + (tt*64 + b)*16384);
    #pragma unroll
    for(int it=0; it<4; ++it){
      int c = tid + it*512;              // 0..2047
      int row = c >> 5, col8 = (c & 31) * 8;
      *(uint4*)&sS1[tt][row][col8] = src[c];
    }
  }
  // rel_type weights for this block's 16 receivers (nh==0 waves only)
  if(nh == 0){
    #pragma unroll 1
    for(int jj=0; jj<16; ++jj){
      int j = j0 + jj, i = l;
      float v = 0.0f;
      if(i != j){ int e = i*63 + j - (j > i ? 1 : 0); v = h2f(RTc[(b*4032 + e)*4 + t]); }
      sRTa[t][jj][i] = v;
    }
  }
  // bfr: this wave's half of w2T[t] (cols nh*32..nh*32+31): 64 VGPRs
  f16x8 bfr[2][8];
  {
    const u16* w2t = W2T + t*16384 + (nh*32)*256;
    #pragma unroll
    for(int nt=0;nt<2;++nt)
      #pragma unroll
      for(int ks=0;ks<8;++ks)
        bfr[nt][ks] = *(const f16x8*)(w2t + (nt*16 + ml)*256 + ks*32 + q*8);
  }
  f32x4 bini[2];            // bias2 pre-folded into acc init
  #pragma unroll
  for(int nt=0;nt<2;++nt){
    float bv = h2f(B2c[t*64 + nh*32 + nt*16 + ml]);
    bini[nt].x = bv; bini[nt].y = bv; bini[nt].z = bv; bini[nt].w = bv;
  }
  const u16* r1b = R1 + (t*64 + b)*16384;
  uint4 ruA[8], ruB[8];
  #pragma unroll
  for(int ks=0;ks<8;++ks) ruA[ks] = *(const uint4*)(r1b + j0*256 + ks*32 + q*8);
  __syncthreads();          // sS1/sRTa/sAggB ready
  auto body = [&](int jj, uint4 (&ru)[8], uint4 (&rn)[8], bool pf){
    f32x4 rw4[4];
    #pragma unroll
    for(int mt=0;mt<4;++mt) rw4[mt] = *(const f32x4*)&sRTa[t][jj][mt*16 + q*4];
    if(pf){                 // prefetch next receiver row into the other buffer
      const u16* r1n = r1b + (j0 + jj + 1)*256;
      #pragma unroll
      for(int ks=0;ks<8;++ks) rn[ks] = *(const uint4*)(r1n + ks*32 + q*8);
    }
    f32x4 acc[4][2];
    #pragma unroll
    for(int mt=0;mt<4;++mt){ acc[mt][0]=bini[0]; acc[mt][1]=bini[1]; }
    #pragma unroll
    for(int ks=0;ks<8;++ks){
      #pragma unroll
      for(int mt=0;mt<4;++mt){
        uint4 sv = *(const uint4*)&sS1[t][mt*16 + ml][ks*32 + q*8];
        f16x8 af = build_frag(sv, ru[ks]);   // relu(S1+R1) in-register
        acc[mt][0] = mfma16(af, bfr[0][ks], acc[mt][0]);
        acc[mt][1] = mfma16(af, bfr[1][ks], acc[mt][1]);
      }
    }
    float cs[2] = {0.f, 0.f};
    #pragma unroll
    for(int mt=0;mt<4;++mt)
      #pragma unroll
      for(int nt=0;nt<2;++nt)
        #pragma unroll
        for(int r=0;r<4;++r)
          cs[nt] += fmaxf(acc[mt][nt][r], 0.0f) * rw4[mt][r];
    #pragma unroll
    for(int nt=0;nt<2;++nt)
      atomicAdd(&sAggB[jj*64 + nh*32 + nt*16 + ml], cs[nt]);
  };
  #pragma unroll 1
  for(int jp=0; jp<8; ++jp){   // explicit ping-pong: no ru=run copies, static indexing
    body(2*jp,     ruA, ruB, true);
    body(2*jp + 1, ruB, ruA, jp < 7);
  }
  __syncthreads();
  float* aggb = AGG + (b*64 + j0)*64;
  #pragma unroll
  for(int it=0; it<2; ++it) aggb[it*512 + tid] = sAggB[it*512 + tid];
}

// ---------------- K3: node MLP (aug=[x,agg] -> 256 -> 256 -> 64) ----------------
__global__ __launch_bounds__(256) void k_node(const u16* __restrict__ Xc, const float* __restrict__ AGG,
    const u16* __restrict__ OW1T, const u16* __restrict__ OB1c,
    const u16* __restrict__ OW2T, const u16* __restrict__ OB2c,
    const u16* __restrict__ OW3T, const u16* __restrict__ OB3c,
    void* __restrict__ out, const int* __restrict__ flag){
  __shared__ __align__(16) u16 sA[64][136];
  __shared__ __align__(16) u16 sH[64][264];
  __shared__ __align__(16) u16 sH2[64][264];
  __shared__ __align__(16) u16 sW[64][264];
  const int tid = threadIdx.x, bb = blockIdx.x;
  const int isbf = *flag;
  {
    const uint4* src = (const uint4*)(Xc + bb*4096);
    #pragma unroll
    for(int it=0; it<2; ++it){
      int c = tid + it*256; int row = c >> 3, col = (c & 7)*8;
      *(uint4*)&sA[row][col] = src[c];
    }
    const float* ag = AGG + bb*4096;
    #pragma unroll
    for(int it=0; it<16; ++it){
      int c = tid + it*256; int row = c >> 6, col = c & 63;
      sA[row][64 + col] = f2h(ag[c]);
    }
  }
  const int wv = tid >> 6, l = tid & 63, ml = l & 15, q = l >> 4;
  const f32x4 z = {0.f,0.f,0.f,0.f};
  __syncthreads();
  for(int nc=0; nc<4; ++nc){
    #pragma unroll
    for(int it=0; it<4; ++it){
      int c = tid + it*256; int h = c >> 4, kc = (c & 15)*8;
      *(uint4*)&sW[h][kc] = *(const uint4*)(OW1T + (nc*64 + h)*128 + kc);
    }
    __syncthreads();
    f32x4 acc[4] = {z,z,z,z};
    #pragma unroll
    for(int ks=0; ks<4; ++ks){
      int kb = ks*32 + q*8;
      f16x8 bfrag = *(const f16x8*)&sW[wv*16 + ml][kb];
      #pragma unroll
      for(int mt=0;mt<4;++mt){
        f16x8 afrag = *(const f16x8*)&sA[mt*16 + ml][kb];
        acc[mt] = mfma16(afrag, bfrag, acc[mt]);
      }
    }
    const int h = nc*64 + wv*16 + ml;
    const float bias = h2f(OB1c[h]);
    #pragma unroll
    for(int mt=0;mt<4;++mt)
      #pragma unroll
      for(int r=0;r<4;++r){
        int row = mt*16 + q*4 + r;
        sH[row][h] = f2h(fmaxf(acc[mt][r] + bias, 0.0f));
      }
    __syncthreads();
  }
  for(int nc=0; nc<4; ++nc){
    #pragma unroll
    for(int it=0; it<8; ++it){
      int c = tid + it*256; int h = c >> 5, kc = (c & 31)*8;
      *(uint4*)&sW[h][kc] = *(const uint4*)(OW2T + (nc*64 + h)*256 + kc);
    }
    __syncthreads();
    f32x4 acc[4] = {z,z,z,z};
    #pragma unroll
    for(int ks=0; ks<8; ++ks){
      int kb = ks*32 + q*8;
      f16x8 bfrag = *(const f16x8*)&sW[wv*16 + ml][kb];
      #pragma unroll
      for(int mt=0;mt<4;++mt){
        f16x8 afrag = *(const f16x8*)&sH[mt*16 + ml][kb];
        acc[mt] = mfma16(afrag, bfrag, acc[mt]);
      }
    }
    const int h = nc*64 + wv*16 + ml;
    const float bias = h2f(OB2c[h]);
    #pragma unroll
    for(int mt=0;mt<4;++mt)
      #pragma unroll
      for(int r=0;r<4;++r){
        int row = mt*16 + q*4 + r;
        sH2[row][h] = f2h(fmaxf(acc[mt][r] + bias, 0.0f));
      }
    __syncthreads();
  }
  {
    #pragma unroll
    for(int it=0; it<8; ++it){
      int c = tid + it*256; int h = c >> 5, kc = (c & 31)*8;
      *(uint4*)&sW[h][kc] = *(const uint4*)(OW3T + h*256 + kc);
    }
    __syncthreads();
    f32x4 acc[4] = {z,z,z,z};
    #pragma unroll
    for(int ks=0; ks<8; ++ks){
      int kb = ks*32 + q*8;
      f16x8 bfrag = *(const f16x8*)&sW[wv*16 + ml][kb];
      #pragma unroll
      for(int mt=0;mt<4;++mt){
        f16x8 afrag = *(const f16x8*)&sH2[mt*16 + ml][kb];
        acc[mt] = mfma16(afrag, bfrag, acc[mt]);
      }
    }
    const int o = wv*16 + ml;
    const float bias = h2f(OB3c[o]);
    #pragma unroll
    for(int mt=0;mt<4;++mt)
      #pragma unroll
      for(int r=0;r<4;++r){
        int row = mt*16 + q*4 + r;
        float v = acc[mt][r] + bias;
        int idx = bb*4096 + row*64 + o;
        if(isbf) ((u16*)out)[idx] = f2bf(v);
        else     ((float*)out)[idx] = v;
      }
  }
}

extern "C" void kernel_launch(void* const* d_in, const int* in_sizes, int n_in,
                              void* d_out, int out_size, void* d_ws, size_t ws_size,
                              hipStream_t stream){
  (void)in_sizes; (void)n_in; (void)out_size; (void)ws_size;
  char* ws = (char*)d_ws;
  u16* W1T  = (u16*)(ws + OFF_W1T);
  u16* W2T  = (u16*)(ws + OFF_W2T);
  u16* OW1T = (u16*)(ws + OFF_OW1T);
  u16* OW2T = (u16*)(ws + OFF_OW2T);
  u16* OW3T = (u16*)(ws + OFF_OW3T);
  u16* B1c  = (u16*)(ws + OFF_B1);
  u16* B2c  = (u16*)(ws + OFF_B2);
  u16* OB1c = (u16*)(ws + OFF_OB1);
  u16* OB2c = (u16*)(ws + OFF_OB2);
  u16* OB3c = (u16*)(ws + OFF_OB3);
  u16* Xc   = (u16*)(ws + OFF_XC);
  u16* RTc  = (u16*)(ws + OFF_RTC);
  u16* S1   = (u16*)(ws + OFF_S1);
  u16* R1   = (u16*)(ws + OFF_R1);
  float* AGG = (float*)(ws + OFF_AGG);

  k_sniff<<<1, 64, 0, stream>>>((const u16*)d_in[0], (int*)ws);
  k_tr<<<304, 256, 0, stream>>>(d_in[4], d_in[6], d_in[8], d_in[10], d_in[12], ws);
  k_cvt2<<<5064, 256, 0, stream>>>(d_in[0], d_in[1], d_in[5], d_in[7],
                                   d_in[9], d_in[11], d_in[13], ws);
  k_s1r1<<<512, 256, 0, stream>>>(Xc, W1T, B1c, S1, R1);
  k_edge<<<256, 512, 0, stream>>>(RTc, W2T, B2c, S1, R1, AGG);
  k_node<<<64, 256, 0, stream>>>(Xc, AGG, OW1T, OB1c, OW2T, OB2c, OW3T, OB3c, d_out, (const int*)ws);
}

// Round 5
// 269.196 us; speedup vs baseline: 1.0050x; 1.0050x over previous
//
#include <hip/hip_runtime.h>

typedef unsigned short u16;
typedef __attribute__((ext_vector_type(8))) _Float16 f16x8;
typedef __attribute__((ext_vector_type(2))) _Float16 f16x2;
typedef __attribute__((ext_vector_type(4))) float f32x4;

#define DEV static __device__ __forceinline__

DEV float bf2f(u16 h){ unsigned u = ((unsigned)h) << 16; return __builtin_bit_cast(float, u); }
DEV u16 f2bf(float f){ unsigned u = __builtin_bit_cast(unsigned, f); u += 0x7FFFu + ((u >> 16) & 1u); return (u16)(u >> 16); }
DEV u16 f2h(float f){ _Float16 h = (_Float16)f; return __builtin_bit_cast(u16, h); }
DEV float h2f(u16 h){ return (float)__builtin_bit_cast(_Float16, h); }

DEV f32x4 mfma16(f16x8 a, f16x8 b, f32x4 c){
  return __builtin_amdgcn_mfma_f32_16x16x32_f16(a, b, c, 0, 0, 0);
}

// relu(S1+R1) on 8 packed halves: 4x v_pk_add_f16 + 4x v_pk_max_f16.
DEV f16x8 build_frag(uint4 s, uint4 r){
  f16x8 a = __builtin_bit_cast(f16x8, s);
  f16x8 b = __builtin_bit_cast(f16x8, r);
  f16x8 v = a + b;
  const f16x8 z = {0,0,0,0,0,0,0,0};
  return __builtin_elementwise_max(v, z);
}

// Sizes: B=64, N=64, F=64, H=256, O=64, T=4, E=4032
// ws layout (bytes): FLAG@0 | W1T@256 | W2T@262400 | OW1T@393472 | OW2T@459008
//  | OW3T@590080 | B1@622848 | B2@624896 | OB1@625408 | OB2@625920 | OB3@626432
//  | Xc@626688 | RTc@1150976 | S1@3215360 | R1@11603968 | AGG(f32)@19992576
#define OFF_W1T  256
#define OFF_W2T  262400
#define OFF_OW1T 393472
#define OFF_OW2T 459008
#define OFF_OW3T 590080
#define OFF_B1   622848
#define OFF_B2   624896
#define OFF_OB1  625408
#define OFF_OB2  625920
#define OFF_OB3  626432
#define OFF_XC   626688
#define OFF_RTC  1150976
#define OFF_S1   3215360
#define OFF_R1   11603968
#define OFF_AGG  19992576

// ---------------- K-1: dtype sniff ----------------
__global__ void k_sniff(const u16* __restrict__ x, int* __restrict__ flag){
  int l = threadIdx.x;
  u16 u = x[2 * l];
  int e = (u >> 7) & 0xFF;
  int ok = (e >= 103 && e <= 143) ? 1 : 0;
  unsigned long long m = __ballot(ok);
  if(l == 0) *flag = (__builtin_popcountll(m) >= 40) ? 1 : 0;  // 1 = bf16 I/O
}

DEV float ldin(const void* p, int i, int isbf){
  return isbf ? bf2f(((const u16*)p)[i]) : ((const float*)p)[i];
}

// ---------------- K0a: tiled transpose+convert for the 5 weight matrices ----------------
// src [G][R][C] -> dst [G][C][R], 32x32 LDS tiles, coalesced read+write.
__global__ __launch_bounds__(256) void k_tr(const void* __restrict__ w1, const void* __restrict__ w2,
    const void* __restrict__ ow1, const void* __restrict__ ow2, const void* __restrict__ ow3,
    char* __restrict__ ws){
  const int isbf = *(const int*)ws;
  __shared__ float tile[32][33];
  int bid = blockIdx.x, tid = threadIdx.x;
  const void* src; u16* dst; int R, C, off, r0, c0;
  if(bid < 128){ int g = bid >> 5, tt = bid & 31;
    src = w1; dst = (u16*)(ws + OFF_W1T); R = 128; C = 256; off = g * 32768;
    r0 = (tt >> 3) << 5; c0 = (tt & 7) << 5;
  } else if(bid < 192){ int bb = bid - 128; int g = bb >> 4, tt = bb & 15;
    src = w2; dst = (u16*)(ws + OFF_W2T); R = 256; C = 64; off = g * 16384;
    r0 = (tt >> 1) << 5; c0 = (tt & 1) << 5;
  } else if(bid < 224){ int bb = bid - 192;
    src = ow1; dst = (u16*)(ws + OFF_OW1T); R = 128; C = 256; off = 0;
    r0 = (bb >> 3) << 5; c0 = (bb & 7) << 5;
  } else if(bid < 288){ int bb = bid - 224;
    src = ow2; dst = (u16*)(ws + OFF_OW2T); R = 256; C = 256; off = 0;
    r0 = (bb >> 3) << 5; c0 = (bb & 7) << 5;
  } else { int bb = bid - 288;
    src = ow3; dst = (u16*)(ws + OFF_OW3T); R = 256; C = 64; off = 0;
    r0 = (bb >> 1) << 5; c0 = (bb & 1) << 5;
  }
  int tx = tid & 31, ty = tid >> 5;
  #pragma unroll
  for(int p = 0; p < 4; ++p){
    int r = ty + p * 8;
    tile[r][tx] = ldin(src, off + (r0 + r) * C + c0 + tx, isbf);
  }
  __syncthreads();
  #pragma unroll
  for(int p = 0; p < 4; ++p){
    int c = ty + p * 8;
    dst[off + (c0 + c) * R + r0 + tx] = f2h(tile[tx][c]);
  }
}

// ---------------- K0b: coalesced elementwise converts (x, rel_type, biases) ----------------
__global__ __launch_bounds__(256) void k_cvt2(const void* __restrict__ x, const void* __restrict__ rt,
    const void* __restrict__ b1, const void* __restrict__ b2,
    const void* __restrict__ ob1, const void* __restrict__ ob2, const void* __restrict__ ob3,
    char* __restrict__ ws){
  const int isbf = *(const int*)ws;
  int n = blockIdx.x * 256 + threadIdx.x;
  if(n < 262144){ ((u16*)(ws+OFF_XC))[n] = f2h(ldin(x, n, isbf)); return; }
  n -= 262144;
  if(n < 1032192){ ((u16*)(ws+OFF_RTC))[n] = f2h(ldin(rt, n, isbf)); return; }
  n -= 1032192;
  if(n < 1024){ ((u16*)(ws+OFF_B1))[n] = f2h(ldin(b1, n, isbf)); return; }
  n -= 1024;
  if(n < 256){ ((u16*)(ws+OFF_B2))[n] = f2h(ldin(b2, n, isbf)); return; }
  n -= 256;
  if(n < 256){ ((u16*)(ws+OFF_OB1))[n] = f2h(ldin(ob1, n, isbf)); return; }
  n -= 256;
  if(n < 256){ ((u16*)(ws+OFF_OB2))[n] = f2h(ldin(ob2, n, isbf)); return; }
  n -= 256;
  if(n < 64){ ((u16*)(ws+OFF_OB3))[n] = f2h(ldin(ob3, n, isbf)); return; }
}

// ---------------- K1: S1/R1 = x @ w1-half (+b1 on receiver half) ----------------
__global__ __launch_bounds__(256) void k_s1r1(const u16* __restrict__ Xc, const u16* __restrict__ W1T,
    const u16* __restrict__ B1c, u16* __restrict__ S1, u16* __restrict__ R1){
  __shared__ __align__(16) u16 sX[64][72];
  __shared__ __align__(16) u16 sW[256][72];
  const int tid = threadIdx.x, bid = blockIdx.x;
  const int b = bid & 63, th = bid >> 6, t = th >> 1, half = th & 1;
  {
    const uint4* src = (const uint4*)(Xc + b*4096);
    #pragma unroll
    for(int it=0; it<2; ++it){
      int c = tid + it*256; int row = c >> 3, col = (c & 7) * 8;
      *(uint4*)&sX[row][col] = src[c];
    }
    const u16* base = W1T + t*32768 + half*64;
    #pragma unroll
    for(int it=0; it<8; ++it){
      int c = tid + it*256; int h = c >> 3, kc = (c & 7) * 8;
      *(uint4*)&sW[h][kc] = *(const uint4*)(base + h*128 + kc);
    }
  }
  __syncthreads();
  const int wv = tid >> 6, l = tid & 63, ml = l & 15, q = l >> 4;
  const f32x4 z = {0.f,0.f,0.f,0.f};
  f32x4 acc[4][4];
  #pragma unroll
  for(int mt=0;mt<4;++mt){ acc[mt][0]=z; acc[mt][1]=z; acc[mt][2]=z; acc[mt][3]=z; }
  #pragma unroll
  for(int ks=0; ks<2; ++ks){
    const int kb = ks*32 + q*8;
    f16x8 af[4], bff[4];
    #pragma unroll
    for(int mt=0;mt<4;++mt) af[mt] = *(const f16x8*)&sX[mt*16 + ml][kb];
    #pragma unroll
    for(int nt=0;nt<4;++nt) bff[nt] = *(const f16x8*)&sW[wv*64 + nt*16 + ml][kb];
    #pragma unroll
    for(int mt=0;mt<4;++mt)
      #pragma unroll
      for(int nt=0;nt<4;++nt)
        acc[mt][nt] = mfma16(af[mt], bff[nt], acc[mt][nt]);
  }
  u16* dst = (half ? R1 : S1) + (t*64 + b)*16384;
  #pragma unroll
  for(int nt=0;nt<4;++nt){
    const int h = wv*64 + nt*16 + ml;
    const float bias = half ? h2f(B1c[t*256 + h]) : 0.0f;
    #pragma unroll
    for(int mt=0;mt<4;++mt)
      #pragma unroll
      for(int r=0;r<4;++r){
        int irow = mt*16 + q*4 + r;
        dst[irow*256 + h] = f2h(acc[mt][nt][r] + bias);
      }
  }
}

// ---------------- K2: per-edge layer-2 + weighted receiver aggregation ----------------
// R5: R4 structure (512-thread block, 8 waves = 2 waves/SIMD, wave = (t,nh))
// with the register budget FIXED. R4's failure was visible in counters:
// __launch_bounds__(512) defaulted to 4 waves/EU -> 128-VGPR cap -> the
// ~200-reg live set (bfr 64 + ruA/ruB 64 + acc 32 + misc) spilled to
// scratch: FETCH 23MB->454MB, k_edge 165us. __launch_bounds__(512, 2)
// (2 waves/EU = exactly 1 block/CU for an 8-wave block) sets the cap to
// 512/2 = 256 VGPRs, which the live set fits. LDS 152KB -> 1 block/CU.
// sS1 pad = 264 halves/row: b128 reads map 8 lanes per 4-bank cluster
// (the wave64-b128 minimum) -> conflict-free.
__global__ __launch_bounds__(512, 2) void k_edge(const u16* __restrict__ RTc, const u16* __restrict__ W2T,
    const u16* __restrict__ B2c, const u16* __restrict__ S1, const u16* __restrict__ R1,
    float* __restrict__ AGG){
  __shared__ __align__(16) u16 sS1[4][64][264];
  __shared__ float sRTa[4][16][64];
  __shared__ float sAggB[1024];
  const int tid = threadIdx.x;
  const int w = tid >> 6, l = tid & 63, ml = l & 15, q = l >> 4;
  const int t = w >> 1, nh = w & 1;
  const int b = blockIdx.x >> 2, j0 = (blockIdx.x & 3) * 16;
  #pragma unroll
  for(int it=0; it<2; ++it) sAggB[it*512 + tid] = 0.0f;
  // stage all 4 S1[t][b] tiles (128 KB) into LDS, coalesced uint4
  #pragma unroll
  for(int tt=0; tt<4; ++tt){
    const uint4* src = (const uint4*)(S1 + (tt*64 + b)*16384);
    #pragma unroll
    for(int it=0; it<4; ++it){
      int c = tid + it*512;              // 0..2047
      int row = c >> 5, col8 = (c & 31) * 8;
      *(uint4*)&sS1[tt][row][col8] = src[c];
    }
  }
  // rel_type weights for this block's 16 receivers (nh==0 waves only)
  if(nh == 0){
    #pragma unroll 1
    for(int jj=0; jj<16; ++jj){
      int j = j0 + jj, i = l;
      float v = 0.0f;
      if(i != j){ int e = i*63 + j - (j > i ? 1 : 0); v = h2f(RTc[(b*4032 + e)*4 + t]); }
      sRTa[t][jj][i] = v;
    }
  }
  // bfr: this wave's half of w2T[t] (cols nh*32..nh*32+31): 64 VGPRs
  f16x8 bfr[2][8];
  {
    const u16* w2t = W2T + t*16384 + (nh*32)*256;
    #pragma unroll
    for(int nt=0;nt<2;++nt)
      #pragma unroll
      for(int ks=0;ks<8;++ks)
        bfr[nt][ks] = *(const f16x8*)(w2t + (nt*16 + ml)*256 + ks*32 + q*8);
  }
  f32x4 bini[2];            // bias2 pre-folded into acc init
  #pragma unroll
  for(int nt=0;nt<2;++nt){
    float bv = h2f(B2c[t*64 + nh*32 + nt*16 + ml]);
    bini[nt].x = bv; bini[nt].y = bv; bini[nt].z = bv; bini[nt].w = bv;
  }
  const u16* r1b = R1 + (t*64 + b)*16384;
  uint4 ruA[8], ruB[8];
  #pragma unroll
  for(int ks=0;ks<8;++ks) ruA[ks] = *(const uint4*)(r1b + j0*256 + ks*32 + q*8);
  __syncthreads();          // sS1/sRTa/sAggB ready
  auto body = [&](int jj, uint4 (&ru)[8], uint4 (&rn)[8], bool pf){
    f32x4 rw4[4];
    #pragma unroll
    for(int mt=0;mt<4;++mt) rw4[mt] = *(const f32x4*)&sRTa[t][jj][mt*16 + q*4];
    if(pf){                 // prefetch next receiver row into the other buffer
      const u16* r1n = r1b + (j0 + jj + 1)*256;
      #pragma unroll
      for(int ks=0;ks<8;++ks) rn[ks] = *(const uint4*)(r1n + ks*32 + q*8);
    }
    f32x4 acc[4][2];
    #pragma unroll
    for(int mt=0;mt<4;++mt){ acc[mt][0]=bini[0]; acc[mt][1]=bini[1]; }
    #pragma unroll
    for(int ks=0;ks<8;++ks){
      #pragma unroll
      for(int mt=0;mt<4;++mt){
        uint4 sv = *(const uint4*)&sS1[t][mt*16 + ml][ks*32 + q*8];
        f16x8 af = build_frag(sv, ru[ks]);   // relu(S1+R1) in-register
        acc[mt][0] = mfma16(af, bfr[0][ks], acc[mt][0]);
        acc[mt][1] = mfma16(af, bfr[1][ks], acc[mt][1]);
      }
    }
    float cs[2] = {0.f, 0.f};
    #pragma unroll
    for(int mt=0;mt<4;++mt)
      #pragma unroll
      for(int nt=0;nt<2;++nt)
        #pragma unroll
        for(int r=0;r<4;++r)
          cs[nt] += fmaxf(acc[mt][nt][r], 0.0f) * rw4[mt][r];
    #pragma unroll
    for(int nt=0;nt<2;++nt)
      atomicAdd(&sAggB[jj*64 + nh*32 + nt*16 + ml], cs[nt]);
  };
  #pragma unroll 1
  for(int jp=0; jp<8; ++jp){   // explicit ping-pong: no ru=run copies, static indexing
    body(2*jp,     ruA, ruB, true);
    body(2*jp + 1, ruB, ruA, jp < 7);
  }
  __syncthreads();
  float* aggb = AGG + (b*64 + j0)*64;
  #pragma unroll
  for(int it=0; it<2; ++it) aggb[it*512 + tid] = sAggB[it*512 + tid];
}

// ---------------- K3: node MLP (aug=[x,agg] -> 256 -> 256 -> 64) ----------------
__global__ __launch_bounds__(256) void k_node(const u16* __restrict__ Xc, const float* __restrict__ AGG,
    const u16* __restrict__ OW1T, const u16* __restrict__ OB1c,
    const u16* __restrict__ OW2T, const u16* __restrict__ OB2c,
    const u16* __restrict__ OW3T, const u16* __restrict__ OB3c,
    void* __restrict__ out, const int* __restrict__ flag){
  __shared__ __align__(16) u16 sA[64][136];
  __shared__ __align__(16) u16 sH[64][264];
  __shared__ __align__(16) u16 sH2[64][264];
  __shared__ __align__(16) u16 sW[64][264];
  const int tid = threadIdx.x, bb = blockIdx.x;
  const int isbf = *flag;
  {
    const uint4* src = (const uint4*)(Xc + bb*4096);
    #pragma unroll
    for(int it=0; it<2; ++it){
      int c = tid + it*256; int row = c >> 3, col = (c & 7)*8;
      *(uint4*)&sA[row][col] = src[c];
    }
    const float* ag = AGG + bb*4096;
    #pragma unroll
    for(int it=0; it<16; ++it){
      int c = tid + it*256; int row = c >> 6, col = c & 63;
      sA[row][64 + col] = f2h(ag[c]);
    }
  }
  const int wv = tid >> 6, l = tid & 63, ml = l & 15, q = l >> 4;
  const f32x4 z = {0.f,0.f,0.f,0.f};
  __syncthreads();
  for(int nc=0; nc<4; ++nc){
    #pragma unroll
    for(int it=0; it<4; ++it){
      int c = tid + it*256; int h = c >> 4, kc = (c & 15)*8;
      *(uint4*)&sW[h][kc] = *(const uint4*)(OW1T + (nc*64 + h)*128 + kc);
    }
    __syncthreads();
    f32x4 acc[4] = {z,z,z,z};
    #pragma unroll
    for(int ks=0; ks<4; ++ks){
      int kb = ks*32 + q*8;
      f16x8 bfrag = *(const f16x8*)&sW[wv*16 + ml][kb];
      #pragma unroll
      for(int mt=0;mt<4;++mt){
        f16x8 afrag = *(const f16x8*)&sA[mt*16 + ml][kb];
        acc[mt] = mfma16(afrag, bfrag, acc[mt]);
      }
    }
    const int h = nc*64 + wv*16 + ml;
    const float bias = h2f(OB1c[h]);
    #pragma unroll
    for(int mt=0;mt<4;++mt)
      #pragma unroll
      for(int r=0;r<4;++r){
        int row = mt*16 + q*4 + r;
        sH[row][h] = f2h(fmaxf(acc[mt][r] + bias, 0.0f));
      }
    __syncthreads();
  }
  for(int nc=0; nc<4; ++nc){
    #pragma unroll
    for(int it=0; it<8; ++it){
      int c = tid + it*256; int h = c >> 5, kc = (c & 31)*8;
      *(uint4*)&sW[h][kc] = *(const uint4*)(OW2T + (nc*64 + h)*256 + kc);
    }
    __syncthreads();
    f32x4 acc[4] = {z,z,z,z};
    #pragma unroll
    for(int ks=0; ks<8; ++ks){
      int kb = ks*32 + q*8;
      f16x8 bfrag = *(const f16x8*)&sW[wv*16 + ml][kb];
      #pragma unroll
      for(int mt=0;mt<4;++mt){
        f16x8 afrag = *(const f16x8*)&sH[mt*16 + ml][kb];
        acc[mt] = mfma16(afrag, bfrag, acc[mt]);
      }
    }
    const int h = nc*64 + wv*16 + ml;
    const float bias = h2f(OB2c[h]);
    #pragma unroll
    for(int mt=0;mt<4;++mt)
      #pragma unroll
      for(int r=0;r<4;++r){
        int row = mt*16 + q*4 + r;
        sH2[row][h] = f2h(fmaxf(acc[mt][r] + bias, 0.0f));
      }
    __syncthreads();
  }
  {
    #pragma unroll
    for(int it=0; it<8; ++it){
      int c = tid + it*256; int h = c >> 5, kc = (c & 31)*8;
      *(uint4*)&sW[h][kc] = *(const uint4*)(OW3T + h*256 + kc);
    }
    __syncthreads();
    f32x4 acc[4] = {z,z,z,z};
    #pragma unroll
    for(int ks=0; ks<8; ++ks){
      int kb = ks*32 + q*8;
      f16x8 bfrag = *(const f16x8*)&sW[wv*16 + ml][kb];
      #pragma unroll
      for(int mt=0;mt<4;++mt){
        f16x8 afrag = *(const f16x8*)&sH2[mt*16 + ml][kb];
        acc[mt] = mfma16(afrag, bfrag, acc[mt]);
      }
    }
    const int o = wv*16 + ml;
    const float bias = h2f(OB3c[o]);
    #pragma unroll
    for(int mt=0;mt<4;++mt)
      #pragma unroll
      for(int r=0;r<4;++r){
        int row = mt*16 + q*4 + r;
        float v = acc[mt][r] + bias;
        int idx = bb*4096 + row*64 + o;
        if(isbf) ((u16*)out)[idx] = f2bf(v);
        else     ((float*)out)[idx] = v;
      }
  }
}

extern "C" void kernel_launch(void* const* d_in, const int* in_sizes, int n_in,
                              void* d_out, int out_size, void* d_ws, size_t ws_size,
                              hipStream_t stream){
  (void)in_sizes; (void)n_in; (void)out_size; (void)ws_size;
  char* ws = (char*)d_ws;
  u16* W1T  = (u16*)(ws + OFF_W1T);
  u16* W2T  = (u16*)(ws + OFF_W2T);
  u16* OW1T = (u16*)(ws + OFF_OW1T);
  u16* OW2T = (u16*)(ws + OFF_OW2T);
  u16* OW3T = (u16*)(ws + OFF_OW3T);
  u16* B1c  = (u16*)(ws + OFF_B1);
  u16* B2c  = (u16*)(ws + OFF_B2);
  u16* OB1c = (u16*)(ws + OFF_OB1);
  u16* OB2c = (u16*)(ws + OFF_OB2);
  u16* OB3c = (u16*)(ws + OFF_OB3);
  u16* Xc   = (u16*)(ws + OFF_XC);
  u16* RTc  = (u16*)(ws + OFF_RTC);
  u16* S1   = (u16*)(ws + OFF_S1);
  u16* R1   = (u16*)(ws + OFF_R1);
  float* AGG = (float*)(ws + OFF_AGG);

  k_sniff<<<1, 64, 0, stream>>>((const u16*)d_in[0], (int*)ws);
  k_tr<<<304, 256, 0, stream>>>(d_in[4], d_in[6], d_in[8], d_in[10], d_in[12], ws);
  k_cvt2<<<5064, 256, 0, stream>>>(d_in[0], d_in[1], d_in[5], d_in[7],
                                   d_in[9], d_in[11], d_in[13], ws);
  k_s1r1<<<512, 256, 0, stream>>>(Xc, W1T, B1c, S1, R1);
  k_edge<<<256, 512, 0, stream>>>(RTc, W2T, B2c, S1, R1, AGG);
  k_node<<<64, 256, 0, stream>>>(Xc, AGG, OW1T, OB1c, OW2T, OB2c, OW3T, OB3c, d_out, (const int*)ws);
}

// Round 6
// 179.507 us; speedup vs baseline: 1.5072x; 1.4996x over previous
//
#include <hip/hip_runtime.h>

typedef unsigned short u16;
typedef __attribute__((ext_vector_type(8))) _Float16 f16x8;
typedef __attribute__((ext_vector_type(2))) _Float16 f16x2;
typedef __attribute__((ext_vector_type(4))) float f32x4;

#define DEV static __device__ __forceinline__

DEV float bf2f(u16 h){ unsigned u = ((unsigned)h) << 16; return __builtin_bit_cast(float, u); }
DEV u16 f2bf(float f){ unsigned u = __builtin_bit_cast(unsigned, f); u += 0x7FFFu + ((u >> 16) & 1u); return (u16)(u >> 16); }
DEV u16 f2h(float f){ _Float16 h = (_Float16)f; return __builtin_bit_cast(u16, h); }
DEV float h2f(u16 h){ return (float)__builtin_bit_cast(_Float16, h); }

DEV f32x4 mfma16(f16x8 a, f16x8 b, f32x4 c){
  return __builtin_amdgcn_mfma_f32_16x16x32_f16(a, b, c, 0, 0, 0);
}

// relu(S1+R1) on 8 packed halves: 4x v_pk_add_f16 + 4x v_pk_max_f16.
DEV f16x8 build_frag(uint4 s, uint4 r){
  f16x8 a = __builtin_bit_cast(f16x8, s);
  f16x8 b = __builtin_bit_cast(f16x8, r);
  f16x8 v = a + b;
  const f16x8 z = {0,0,0,0,0,0,0,0};
  return __builtin_elementwise_max(v, z);
}

// Sizes: B=64, N=64, F=64, H=256, O=64, T=4, E=4032
// ws layout (bytes): FLAG@0 | W1T@256 | W2T@262400 | OW1T@393472 | OW2T@459008
//  | OW3T@590080 | B1@622848 | B2@624896 | OB1@625408 | OB2@625920 | OB3@626432
//  | Xc@626688 | RTc@1150976 | S1@3215360 | R1@11603968 | AGG(f32)@19992576
#define OFF_W1T  256
#define OFF_W2T  262400
#define OFF_OW1T 393472
#define OFF_OW2T 459008
#define OFF_OW3T 590080
#define OFF_B1   622848
#define OFF_B2   624896
#define OFF_OB1  625408
#define OFF_OB2  625920
#define OFF_OB3  626432
#define OFF_XC   626688
#define OFF_RTC  1150976
#define OFF_S1   3215360
#define OFF_R1   11603968
#define OFF_AGG  19992576

// ---------------- K-1: dtype sniff ----------------
__global__ void k_sniff(const u16* __restrict__ x, int* __restrict__ flag){
  int l = threadIdx.x;
  u16 u = x[2 * l];
  int e = (u >> 7) & 0xFF;
  int ok = (e >= 103 && e <= 143) ? 1 : 0;
  unsigned long long m = __ballot(ok);
  if(l == 0) *flag = (__builtin_popcountll(m) >= 40) ? 1 : 0;  // 1 = bf16 I/O
}

DEV float ldin(const void* p, int i, int isbf){
  return isbf ? bf2f(((const u16*)p)[i]) : ((const float*)p)[i];
}

// ---------------- K0a: tiled transpose+convert for the 5 weight matrices ----------------
// src [G][R][C] -> dst [G][C][R], 32x32 LDS tiles, coalesced read+write.
__global__ __launch_bounds__(256) void k_tr(const void* __restrict__ w1, const void* __restrict__ w2,
    const void* __restrict__ ow1, const void* __restrict__ ow2, const void* __restrict__ ow3,
    char* __restrict__ ws){
  const int isbf = *(const int*)ws;
  __shared__ float tile[32][33];
  int bid = blockIdx.x, tid = threadIdx.x;
  const void* src; u16* dst; int R, C, off, r0, c0;
  if(bid < 128){ int g = bid >> 5, tt = bid & 31;
    src = w1; dst = (u16*)(ws + OFF_W1T); R = 128; C = 256; off = g * 32768;
    r0 = (tt >> 3) << 5; c0 = (tt & 7) << 5;
  } else if(bid < 192){ int bb = bid - 128; int g = bb >> 4, tt = bb & 15;
    src = w2; dst = (u16*)(ws + OFF_W2T); R = 256; C = 64; off = g * 16384;
    r0 = (tt >> 1) << 5; c0 = (tt & 1) << 5;
  } else if(bid < 224){ int bb = bid - 192;
    src = ow1; dst = (u16*)(ws + OFF_OW1T); R = 128; C = 256; off = 0;
    r0 = (bb >> 3) << 5; c0 = (bb & 7) << 5;
  } else if(bid < 288){ int bb = bid - 224;
    src = ow2; dst = (u16*)(ws + OFF_OW2T); R = 256; C = 256; off = 0;
    r0 = (bb >> 3) << 5; c0 = (bb & 7) << 5;
  } else { int bb = bid - 288;
    src = ow3; dst = (u16*)(ws + OFF_OW3T); R = 256; C = 64; off = 0;
    r0 = (bb >> 1) << 5; c0 = (bb & 1) << 5;
  }
  int tx = tid & 31, ty = tid >> 5;
  #pragma unroll
  for(int p = 0; p < 4; ++p){
    int r = ty + p * 8;
    tile[r][tx] = ldin(src, off + (r0 + r) * C + c0 + tx, isbf);
  }
  __syncthreads();
  #pragma unroll
  for(int p = 0; p < 4; ++p){
    int c = ty + p * 8;
    dst[off + (c0 + c) * R + r0 + tx] = f2h(tile[tx][c]);
  }
}

// ---------------- K0b: coalesced elementwise converts (x, rel_type, biases) + AGG zero ----------------
__global__ __launch_bounds__(256) void k_cvt2(const void* __restrict__ x, const void* __restrict__ rt,
    const void* __restrict__ b1, const void* __restrict__ b2,
    const void* __restrict__ ob1, const void* __restrict__ ob2, const void* __restrict__ ob3,
    char* __restrict__ ws){
  const int isbf = *(const int*)ws;
  int n = blockIdx.x * 256 + threadIdx.x;
  if(n < 262144){ ((u16*)(ws+OFF_XC))[n] = f2h(ldin(x, n, isbf)); return; }
  n -= 262144;
  if(n < 1032192){ ((u16*)(ws+OFF_RTC))[n] = f2h(ldin(rt, n, isbf)); return; }
  n -= 1032192;
  if(n < 1024){ ((u16*)(ws+OFF_B1))[n] = f2h(ldin(b1, n, isbf)); return; }
  n -= 1024;
  if(n < 256){ ((u16*)(ws+OFF_B2))[n] = f2h(ldin(b2, n, isbf)); return; }
  n -= 256;
  if(n < 256){ ((u16*)(ws+OFF_OB1))[n] = f2h(ldin(ob1, n, isbf)); return; }
  n -= 256;
  if(n < 256){ ((u16*)(ws+OFF_OB2))[n] = f2h(ldin(ob2, n, isbf)); return; }
  n -= 256;
  if(n < 64){ ((u16*)(ws+OFF_OB3))[n] = f2h(ldin(ob3, n, isbf)); return; }
  n -= 64;
  if(n < 262144){ ((float*)(ws+OFF_AGG))[n] = 0.0f; return; }  // k_edge accumulates via atomics
}

// ---------------- K1: S1/R1 = x @ w1-half (+b1 on receiver half) ----------------
__global__ __launch_bounds__(256) void k_s1r1(const u16* __restrict__ Xc, const u16* __restrict__ W1T,
    const u16* __restrict__ B1c, u16* __restrict__ S1, u16* __restrict__ R1){
  __shared__ __align__(16) u16 sX[64][72];
  __shared__ __align__(16) u16 sW[256][72];
  const int tid = threadIdx.x, bid = blockIdx.x;
  const int b = bid & 63, th = bid >> 6, t = th >> 1, half = th & 1;
  {
    const uint4* src = (const uint4*)(Xc + b*4096);
    #pragma unroll
    for(int it=0; it<2; ++it){
      int c = tid + it*256; int row = c >> 3, col = (c & 7) * 8;
      *(uint4*)&sX[row][col] = src[c];
    }
    const u16* base = W1T + t*32768 + half*64;
    #pragma unroll
    for(int it=0; it<8; ++it){
      int c = tid + it*256; int h = c >> 3, kc = (c & 7) * 8;
      *(uint4*)&sW[h][kc] = *(const uint4*)(base + h*128 + kc);
    }
  }
  __syncthreads();
  const int wv = tid >> 6, l = tid & 63, ml = l & 15, q = l >> 4;
  const f32x4 z = {0.f,0.f,0.f,0.f};
  f32x4 acc[4][4];
  #pragma unroll
  for(int mt=0;mt<4;++mt){ acc[mt][0]=z; acc[mt][1]=z; acc[mt][2]=z; acc[mt][3]=z; }
  #pragma unroll
  for(int ks=0; ks<2; ++ks){
    const int kb = ks*32 + q*8;
    f16x8 af[4], bff[4];
    #pragma unroll
    for(int mt=0;mt<4;++mt) af[mt] = *(const f16x8*)&sX[mt*16 + ml][kb];
    #pragma unroll
    for(int nt=0;nt<4;++nt) bff[nt] = *(const f16x8*)&sW[wv*64 + nt*16 + ml][kb];
    #pragma unroll
    for(int mt=0;mt<4;++mt)
      #pragma unroll
      for(int nt=0;nt<4;++nt)
        acc[mt][nt] = mfma16(af[mt], bff[nt], acc[mt][nt]);
  }
  u16* dst = (half ? R1 : S1) + (t*64 + b)*16384;
  #pragma unroll
  for(int nt=0;nt<4;++nt){
    const int h = wv*64 + nt*16 + ml;
    const float bias = half ? h2f(B1c[t*256 + h]) : 0.0f;
    #pragma unroll
    for(int mt=0;mt<4;++mt)
      #pragma unroll
      for(int r=0;r<4;++r){
        int irow = mt*16 + q*4 + r;
        dst[irow*256 + h] = f2h(acc[mt][nt][r] + bias);
      }
  }
}

// ---------------- K2: per-edge layer-2 + weighted receiver aggregation ----------------
// R6: type-split blocks. block = (b, j-group of 16, tp in {0,1}); 256 threads,
// wave = (tloc, nh): t = 2*tp + tloc, nh = output-col half. Lessons R1/R4/R5:
// any k_edge design whose per-wave live set exceeds ~230 regs spills (the
// HW budget at 2 waves/SIMD is 256 total incl. MFMA accumulators); three
// rounds failed that way (FETCH 23MB -> 450MB). This design fits by
// construction: bfr[2][8]=64 + ru[8]=32 + acc[4][2]=32 + misc ~50 => ~180.
// LDS/block = sS1 2 types (66KB) + sRTa (8KB) + sAggB (4KB) = 79.9KB <= 80KB
// => exactly 2 blocks/CU => 2 waves/SIMD with registers intact; the co-wave
// hides R1-row latency so no ping-pong double buffer (saves 32 regs + movs).
// The two tp blocks produce partial sums -> combined via global f32
// atomicAdd into AGG (zeroed by k_cvt2). Work/CU unchanged; only frag-build
// VALU duplicated 2x (VALU was 34% busy: headroom).
__global__ __launch_bounds__(256, 2) void k_edge(const u16* __restrict__ RTc, const u16* __restrict__ W2T,
    const u16* __restrict__ B2c, const u16* __restrict__ S1, const u16* __restrict__ R1,
    float* __restrict__ AGG){
  __shared__ __align__(16) u16 sS1[2][64][264];
  __shared__ float sRTa[2][16][64];
  __shared__ float sAggB[1024];
  const int tid = threadIdx.x;
  const int w = tid >> 6, l = tid & 63, ml = l & 15, q = l >> 4;
  const int tloc = w >> 1, nh = w & 1;
  const int bid = blockIdx.x;
  const int b = bid >> 3, jg = (bid >> 1) & 3, tp = bid & 1;
  const int t = tp*2 + tloc;
  const int j0 = jg * 16;
  #pragma unroll
  for(int it=0; it<4; ++it) sAggB[it*256 + tid] = 0.0f;
  // stage this block's 2 S1 tiles (64 KB) into LDS, coalesced uint4
  #pragma unroll
  for(int tt=0; tt<2; ++tt){
    const uint4* src = (const uint4*)(S1 + ((tp*2 + tt)*64 + b)*16384);
    #pragma unroll
    for(int it=0; it<8; ++it){
      int c = tid + it*256;              // 0..2047
      int row = c >> 5, col8 = (c & 31) * 8;
      *(uint4*)&sS1[tt][row][col8] = src[c];
    }
  }
  // rel_type weights for this block's 16 receivers (one wave per tloc)
  if(nh == 0){
    #pragma unroll 1
    for(int jj=0; jj<16; ++jj){
      int j = j0 + jj, i = l;
      float v = 0.0f;
      if(i != j){ int e = i*63 + j - (j > i ? 1 : 0); v = h2f(RTc[(b*4032 + e)*4 + t]); }
      sRTa[tloc][jj][i] = v;
    }
  }
  // bfr: this wave's half of w2T[t] (cols nh*32..nh*32+31): 64 VGPRs
  f16x8 bfr[2][8];
  {
    const u16* w2t = W2T + t*16384 + (nh*32)*256;
    #pragma unroll
    for(int nt=0;nt<2;++nt)
      #pragma unroll
      for(int ks=0;ks<8;++ks)
        bfr[nt][ks] = *(const f16x8*)(w2t + (nt*16 + ml)*256 + ks*32 + q*8);
  }
  f32x4 bini[2];            // bias2 pre-folded into acc init
  #pragma unroll
  for(int nt=0;nt<2;++nt){
    float bv = h2f(B2c[t*64 + nh*32 + nt*16 + ml]);
    bini[nt].x = bv; bini[nt].y = bv; bini[nt].z = bv; bini[nt].w = bv;
  }
  const u16* r1b = R1 + (t*64 + b)*16384;
  __syncthreads();          // sS1/sRTa/sAggB ready
  #pragma unroll 1
  for(int jj=0; jj<16; ++jj){
    // this receiver's R1 row (L2-hot; co-resident wave hides the latency)
    uint4 ru[8];
    const u16* r1r = r1b + (j0 + jj)*256;
    #pragma unroll
    for(int ks=0;ks<8;++ks) ru[ks] = *(const uint4*)(r1r + ks*32 + q*8);
    f32x4 acc[4][2];
    #pragma unroll
    for(int mt=0;mt<4;++mt){ acc[mt][0]=bini[0]; acc[mt][1]=bini[1]; }
    #pragma unroll
    for(int ks=0;ks<8;++ks){
      #pragma unroll
      for(int mt=0;mt<4;++mt){
        uint4 sv = *(const uint4*)&sS1[tloc][mt*16 + ml][ks*32 + q*8];
        f16x8 af = build_frag(sv, ru[ks]);   // relu(S1+R1) in-register
        acc[mt][0] = mfma16(af, bfr[0][ks], acc[mt][0]);
        acc[mt][1] = mfma16(af, bfr[1][ks], acc[mt][1]);
      }
    }
    // epilogue: relu(C) (bias pre-folded), weighted column-sum over senders
    f32x4 rw4[4];
    #pragma unroll
    for(int mt=0;mt<4;++mt) rw4[mt] = *(const f32x4*)&sRTa[tloc][jj][mt*16 + q*4];
    float cs[2] = {0.f, 0.f};
    #pragma unroll
    for(int mt=0;mt<4;++mt)
      #pragma unroll
      for(int nt=0;nt<2;++nt)
        #pragma unroll
        for(int r=0;r<4;++r)
          cs[nt] += fmaxf(acc[mt][nt][r], 0.0f) * rw4[mt][r];
    #pragma unroll
    for(int nt=0;nt<2;++nt)
      atomicAdd(&sAggB[jj*64 + nh*32 + nt*16 + ml], cs[nt]);
  }
  __syncthreads();
  // combine the two tp blocks' partials in global memory (AGG pre-zeroed)
  float* aggb = AGG + (b*64 + j0)*64;
  #pragma unroll
  for(int it=0; it<4; ++it) atomicAdd(&aggb[it*256 + tid], sAggB[it*256 + tid]);
}

// ---------------- K3: node MLP (aug=[x,agg] -> 256 -> 256 -> 64) ----------------
__global__ __launch_bounds__(256) void k_node(const u16* __restrict__ Xc, const float* __restrict__ AGG,
    const u16* __restrict__ OW1T, const u16* __restrict__ OB1c,
    const u16* __restrict__ OW2T, const u16* __restrict__ OB2c,
    const u16* __restrict__ OW3T, const u16* __restrict__ OB3c,
    void* __restrict__ out, const int* __restrict__ flag){
  __shared__ __align__(16) u16 sA[64][136];
  __shared__ __align__(16) u16 sH[64][264];
  __shared__ __align__(16) u16 sH2[64][264];
  __shared__ __align__(16) u16 sW[64][264];
  const int tid = threadIdx.x, bb = blockIdx.x;
  const int isbf = *flag;
  {
    const uint4* src = (const uint4*)(Xc + bb*4096);
    #pragma unroll
    for(int it=0; it<2; ++it){
      int c = tid + it*256; int row = c >> 3, col = (c & 7)*8;
      *(uint4*)&sA[row][col] = src[c];
    }
    const float* ag = AGG + bb*4096;
    #pragma unroll
    for(int it=0; it<16; ++it){
      int c = tid + it*256; int row = c >> 6, col = c & 63;
      sA[row][64 + col] = f2h(ag[c]);
    }
  }
  const int wv = tid >> 6, l = tid & 63, ml = l & 15, q = l >> 4;
  const f32x4 z = {0.f,0.f,0.f,0.f};
  __syncthreads();
  for(int nc=0; nc<4; ++nc){
    #pragma unroll
    for(int it=0; it<4; ++it){
      int c = tid + it*256; int h = c >> 4, kc = (c & 15)*8;
      *(uint4*)&sW[h][kc] = *(const uint4*)(OW1T + (nc*64 + h)*128 + kc);
    }
    __syncthreads();
    f32x4 acc[4] = {z,z,z,z};
    #pragma unroll
    for(int ks=0; ks<4; ++ks){
      int kb = ks*32 + q*8;
      f16x8 bfrag = *(const f16x8*)&sW[wv*16 + ml][kb];
      #pragma unroll
      for(int mt=0;mt<4;++mt){
        f16x8 afrag = *(const f16x8*)&sA[mt*16 + ml][kb];
        acc[mt] = mfma16(afrag, bfrag, acc[mt]);
      }
    }
    const int h = nc*64 + wv*16 + ml;
    const float bias = h2f(OB1c[h]);
    #pragma unroll
    for(int mt=0;mt<4;++mt)
      #pragma unroll
      for(int r=0;r<4;++r){
        int row = mt*16 + q*4 + r;
        sH[row][h] = f2h(fmaxf(acc[mt][r] + bias, 0.0f));
      }
    __syncthreads();
  }
  for(int nc=0; nc<4; ++nc){
    #pragma unroll
    for(int it=0; it<8; ++it){
      int c = tid + it*256; int h = c >> 5, kc = (c & 31)*8;
      *(uint4*)&sW[h][kc] = *(const uint4*)(OW2T + (nc*64 + h)*256 + kc);
    }
    __syncthreads();
    f32x4 acc[4] = {z,z,z,z};
    #pragma unroll
    for(int ks=0; ks<8; ++ks){
      int kb = ks*32 + q*8;
      f16x8 bfrag = *(const f16x8*)&sW[wv*16 + ml][kb];
      #pragma unroll
      for(int mt=0;mt<4;++mt){
        f16x8 afrag = *(const f16x8*)&sH[mt*16 + ml][kb];
        acc[mt] = mfma16(afrag, bfrag, acc[mt]);
      }
    }
    const int h = nc*64 + wv*16 + ml;
    const float bias = h2f(OB2c[h]);
    #pragma unroll
    for(int mt=0;mt<4;++mt)
      #pragma unroll
      for(int r=0;r<4;++r){
        int row = mt*16 + q*4 + r;
        sH2[row][h] = f2h(fmaxf(acc[mt][r] + bias, 0.0f));
      }
    __syncthreads();
  }
  {
    #pragma unroll
    for(int it=0; it<8; ++it){
      int c = tid + it*256; int h = c >> 5, kc = (c & 31)*8;
      *(uint4*)&sW[h][kc] = *(const uint4*)(OW3T + h*256 + kc);
    }
    __syncthreads();
    f32x4 acc[4] = {z,z,z,z};
    #pragma unroll
    for(int ks=0; ks<8; ++ks){
      int kb = ks*32 + q*8;
      f16x8 bfrag = *(const f16x8*)&sW[wv*16 + ml][kb];
      #pragma unroll
      for(int mt=0;mt<4;++mt){
        f16x8 afrag = *(const f16x8*)&sH2[mt*16 + ml][kb];
        acc[mt] = mfma16(afrag, bfrag, acc[mt]);
      }
    }
    const int o = wv*16 + ml;
    const float bias = h2f(OB3c[o]);
    #pragma unroll
    for(int mt=0;mt<4;++mt)
      #pragma unroll
      for(int r=0;r<4;++r){
        int row = mt*16 + q*4 + r;
        float v = acc[mt][r] + bias;
        int idx = bb*4096 + row*64 + o;
        if(isbf) ((u16*)out)[idx] = f2bf(v);
        else     ((float*)out)[idx] = v;
      }
  }
}

extern "C" void kernel_launch(void* const* d_in, const int* in_sizes, int n_in,
                              void* d_out, int out_size, void* d_ws, size_t ws_size,
                              hipStream_t stream){
  (void)in_sizes; (void)n_in; (void)out_size; (void)ws_size;
  char* ws = (char*)d_ws;
  u16* W1T  = (u16*)(ws + OFF_W1T);
  u16* W2T  = (u16*)(ws + OFF_W2T);
  u16* OW1T = (u16*)(ws + OFF_OW1T);
  u16* OW2T = (u16*)(ws + OFF_OW2T);
  u16* OW3T = (u16*)(ws + OFF_OW3T);
  u16* B1c  = (u16*)(ws + OFF_B1);
  u16* B2c  = (u16*)(ws + OFF_B2);
  u16* OB1c = (u16*)(ws + OFF_OB1);
  u16* OB2c = (u16*)(ws + OFF_OB2);
  u16* OB3c = (u16*)(ws + OFF_OB3);
  u16* Xc   = (u16*)(ws + OFF_XC);
  u16* RTc  = (u16*)(ws + OFF_RTC);
  u16* S1   = (u16*)(ws + OFF_S1);
  u16* R1   = (u16*)(ws + OFF_R1);
  float* AGG = (float*)(ws + OFF_AGG);

  k_sniff<<<1, 64, 0, stream>>>((const u16*)d_in[0], (int*)ws);
  k_tr<<<304, 256, 0, stream>>>(d_in[4], d_in[6], d_in[8], d_in[10], d_in[12], ws);
  k_cvt2<<<6088, 256, 0, stream>>>(d_in[0], d_in[1], d_in[5], d_in[7],
                                   d_in[9], d_in[11], d_in[13], ws);
  k_s1r1<<<512, 256, 0, stream>>>(Xc, W1T, B1c, S1, R1);
  k_edge<<<512, 256, 0, stream>>>(RTc, W2T, B2c, S1, R1, AGG);
  k_node<<<64, 256, 0, stream>>>(Xc, AGG, OW1T, OB1c, OW2T, OB2c, OW3T, OB3c, d_out, (const int*)ws);
}

// Round 7
// 175.869 us; speedup vs baseline: 1.5383x; 1.0207x over previous
//
#include <hip/hip_runtime.h>

typedef unsigned short u16;
typedef __attribute__((ext_vector_type(8))) _Float16 f16x8;
typedef __attribute__((ext_vector_type(2))) _Float16 f16x2;
typedef __attribute__((ext_vector_type(4))) float f32x4;

#define DEV static __device__ __forceinline__

DEV float bf2f(u16 h){ unsigned u = ((unsigned)h) << 16; return __builtin_bit_cast(float, u); }
DEV u16 f2bf(float f){ unsigned u = __builtin_bit_cast(unsigned, f); u += 0x7FFFu + ((u >> 16) & 1u); return (u16)(u >> 16); }
DEV u16 f2h(float f){ _Float16 h = (_Float16)f; return __builtin_bit_cast(u16, h); }
DEV float h2f(u16 h){ return (float)__builtin_bit_cast(_Float16, h); }

DEV f32x4 mfma16(f16x8 a, f16x8 b, f32x4 c){
  return __builtin_amdgcn_mfma_f32_16x16x32_f16(a, b, c, 0, 0, 0);
}

// relu(S1+R1) on 8 packed halves: 4x v_pk_add_f16 + 4x v_pk_max_f16.
DEV f16x8 build_frag(uint4 s, uint4 r){
  f16x8 a = __builtin_bit_cast(f16x8, s);
  f16x8 b = __builtin_bit_cast(f16x8, r);
  f16x8 v = a + b;
  const f16x8 z = {0,0,0,0,0,0,0,0};
  return __builtin_elementwise_max(v, z);
}

// Sizes: B=64, N=64, F=64, H=256, O=64, T=4, E=4032
// ws layout (bytes): FLAG@0 | W1T@256 | W2T@262400 | OW1T@393472 | OW2T@459008
//  | OW3T@590080 | B1@622848 | B2@624896 | OB1@625408 | OB2@625920 | OB3@626432
//  | Xc@626688 | RTc@1150976 | S1@3215360 | R1@11603968 | AGG(f32)@19992576
#define OFF_W1T  256
#define OFF_W2T  262400
#define OFF_OW1T 393472
#define OFF_OW2T 459008
#define OFF_OW3T 590080
#define OFF_B1   622848
#define OFF_B2   624896
#define OFF_OB1  625408
#define OFF_OB2  625920
#define OFF_OB3  626432
#define OFF_XC   626688
#define OFF_RTC  1150976
#define OFF_S1   3215360
#define OFF_R1   11603968
#define OFF_AGG  19992576

// ---------------- K-1: dtype sniff ----------------
__global__ void k_sniff(const u16* __restrict__ x, int* __restrict__ flag){
  int l = threadIdx.x;
  u16 u = x[2 * l];
  int e = (u >> 7) & 0xFF;
  int ok = (e >= 103 && e <= 143) ? 1 : 0;
  unsigned long long m = __ballot(ok);
  if(l == 0) *flag = (__builtin_popcountll(m) >= 40) ? 1 : 0;  // 1 = bf16 I/O
}

DEV float ldin(const void* p, int i, int isbf){
  return isbf ? bf2f(((const u16*)p)[i]) : ((const float*)p)[i];
}

// ---------------- K0a: tiled transpose+convert for the 5 weight matrices ----------------
// src [G][R][C] -> dst [G][C][R], 32x32 LDS tiles, coalesced read+write.
__global__ __launch_bounds__(256) void k_tr(const void* __restrict__ w1, const void* __restrict__ w2,
    const void* __restrict__ ow1, const void* __restrict__ ow2, const void* __restrict__ ow3,
    char* __restrict__ ws){
  const int isbf = *(const int*)ws;
  __shared__ float tile[32][33];
  int bid = blockIdx.x, tid = threadIdx.x;
  const void* src; u16* dst; int R, C, off, r0, c0;
  if(bid < 128){ int g = bid >> 5, tt = bid & 31;
    src = w1; dst = (u16*)(ws + OFF_W1T); R = 128; C = 256; off = g * 32768;
    r0 = (tt >> 3) << 5; c0 = (tt & 7) << 5;
  } else if(bid < 192){ int bb = bid - 128; int g = bb >> 4, tt = bb & 15;
    src = w2; dst = (u16*)(ws + OFF_W2T); R = 256; C = 64; off = g * 16384;
    r0 = (tt >> 1) << 5; c0 = (tt & 1) << 5;
  } else if(bid < 224){ int bb = bid - 192;
    src = ow1; dst = (u16*)(ws + OFF_OW1T); R = 128; C = 256; off = 0;
    r0 = (bb >> 3) << 5; c0 = (bb & 7) << 5;
  } else if(bid < 288){ int bb = bid - 224;
    src = ow2; dst = (u16*)(ws + OFF_OW2T); R = 256; C = 256; off = 0;
    r0 = (bb >> 3) << 5; c0 = (bb & 7) << 5;
  } else { int bb = bid - 288;
    src = ow3; dst = (u16*)(ws + OFF_OW3T); R = 256; C = 64; off = 0;
    r0 = (bb >> 1) << 5; c0 = (bb & 1) << 5;
  }
  int tx = tid & 31, ty = tid >> 5;
  #pragma unroll
  for(int p = 0; p < 4; ++p){
    int r = ty + p * 8;
    tile[r][tx] = ldin(src, off + (r0 + r) * C + c0 + tx, isbf);
  }
  __syncthreads();
  #pragma unroll
  for(int p = 0; p < 4; ++p){
    int c = ty + p * 8;
    dst[off + (c0 + c) * R + r0 + tx] = f2h(tile[tx][c]);
  }
}

// ---------------- K0b: coalesced elementwise converts (x, rel_type, biases) ----------------
__global__ __launch_bounds__(256) void k_cvt2(const void* __restrict__ x, const void* __restrict__ rt,
    const void* __restrict__ b1, const void* __restrict__ b2,
    const void* __restrict__ ob1, const void* __restrict__ ob2, const void* __restrict__ ob3,
    char* __restrict__ ws){
  const int isbf = *(const int*)ws;
  int n = blockIdx.x * 256 + threadIdx.x;
  if(n < 262144){ ((u16*)(ws+OFF_XC))[n] = f2h(ldin(x, n, isbf)); return; }
  n -= 262144;
  if(n < 1032192){ ((u16*)(ws+OFF_RTC))[n] = f2h(ldin(rt, n, isbf)); return; }
  n -= 1032192;
  if(n < 1024){ ((u16*)(ws+OFF_B1))[n] = f2h(ldin(b1, n, isbf)); return; }
  n -= 1024;
  if(n < 256){ ((u16*)(ws+OFF_B2))[n] = f2h(ldin(b2, n, isbf)); return; }
  n -= 256;
  if(n < 256){ ((u16*)(ws+OFF_OB1))[n] = f2h(ldin(ob1, n, isbf)); return; }
  n -= 256;
  if(n < 256){ ((u16*)(ws+OFF_OB2))[n] = f2h(ldin(ob2, n, isbf)); return; }
  n -= 256;
  if(n < 64){ ((u16*)(ws+OFF_OB3))[n] = f2h(ldin(ob3, n, isbf)); return; }
}

// ---------------- K1: S1/R1 = x @ w1-half (+b1 on receiver half) ----------------
__global__ __launch_bounds__(256) void k_s1r1(const u16* __restrict__ Xc, const u16* __restrict__ W1T,
    const u16* __restrict__ B1c, u16* __restrict__ S1, u16* __restrict__ R1){
  __shared__ __align__(16) u16 sX[64][72];
  __shared__ __align__(16) u16 sW[256][72];
  const int tid = threadIdx.x, bid = blockIdx.x;
  const int b = bid & 63, th = bid >> 6, t = th >> 1, half = th & 1;
  {
    const uint4* src = (const uint4*)(Xc + b*4096);
    #pragma unroll
    for(int it=0; it<2; ++it){
      int c = tid + it*256; int row = c >> 3, col = (c & 7) * 8;
      *(uint4*)&sX[row][col] = src[c];
    }
    const u16* base = W1T + t*32768 + half*64;
    #pragma unroll
    for(int it=0; it<8; ++it){
      int c = tid + it*256; int h = c >> 3, kc = (c & 7) * 8;
      *(uint4*)&sW[h][kc] = *(const uint4*)(base + h*128 + kc);
    }
  }
  __syncthreads();
  const int wv = tid >> 6, l = tid & 63, ml = l & 15, q = l >> 4;
  const f32x4 z = {0.f,0.f,0.f,0.f};
  f32x4 acc[4][4];
  #pragma unroll
  for(int mt=0;mt<4;++mt){ acc[mt][0]=z; acc[mt][1]=z; acc[mt][2]=z; acc[mt][3]=z; }
  #pragma unroll
  for(int ks=0; ks<2; ++ks){
    const int kb = ks*32 + q*8;
    f16x8 af[4], bff[4];
    #pragma unroll
    for(int mt=0;mt<4;++mt) af[mt] = *(const f16x8*)&sX[mt*16 + ml][kb];
    #pragma unroll
    for(int nt=0;nt<4;++nt) bff[nt] = *(const f16x8*)&sW[wv*64 + nt*16 + ml][kb];
    #pragma unroll
    for(int mt=0;mt<4;++mt)
      #pragma unroll
      for(int nt=0;nt<4;++nt)
        acc[mt][nt] = mfma16(af[mt], bff[nt], acc[mt][nt]);
  }
  u16* dst = (half ? R1 : S1) + (t*64 + b)*16384;
  #pragma unroll
  for(int nt=0;nt<4;++nt){
    const int h = wv*64 + nt*16 + ml;
    const float bias = half ? h2f(B1c[t*256 + h]) : 0.0f;
    #pragma unroll
    for(int mt=0;mt<4;++mt)
      #pragma unroll
      for(int r=0;r<4;++r){
        int irow = mt*16 + q*4 + r;
        dst[irow*256 + h] = f2h(acc[mt][nt][r] + bias);
      }
  }
}

// ---------------- K2: per-edge layer-2 + weighted receiver aggregation ----------------
// R7: back to the R3 shape (grid 256, wave = type t, su/bfr register-resident,
// 1 wave/SIMD) -- R6 proved more-waves loses (cyc/MFMA 16.4 -> 21): the
// kernel is PER-WAVE LATENCY bound (union-counter math: per-SIMD MFMA ~8%,
// VALU ~9% in R3 => wave issues nothing ~80% of cycles). Attack ILP instead:
//  - process TWO receivers per iteration (independent acc chains A/B,
//    interleaved at the mt level => 2x independent work between every
//    dependency; su read amortized over both builds)
//  - stage the block's 16 R1 rows x 4 types to LDS up-front (34KB): the
//    inner loop has ZERO global loads; ru is a broadcast-pattern
//    ds_read_b128 (q-only address => 16-lane broadcast, conflict-free),
//    hoistable by the scheduler across the fully-unrolled ks body.
// Budget at 1 wave/SIMD = 512 unified regs: su 128 + bfr 128 + acc 128 +
// transients ~80 => ~460-490 peak. launch_bounds(256,1) keeps the cap at 512.
__global__ __launch_bounds__(256, 1) void k_edge(const u16* __restrict__ RTc, const u16* __restrict__ W2T,
    const u16* __restrict__ B2c, const u16* __restrict__ S1, const u16* __restrict__ R1,
    float* __restrict__ AGG){
  __shared__ __align__(16) u16 sR1[4][16][264];
  __shared__ float sRTa[4][16][64];
  __shared__ float sAggB[1024];
  const int tid = threadIdx.x;
  const int t = tid >> 6, l = tid & 63, ml = l & 15, q = l >> 4;
  const int b = blockIdx.x >> 2, j0 = (blockIdx.x & 3) * 16;
  #pragma unroll
  for(int it=0; it<4; ++it) sAggB[it*256 + tid] = 0.0f;
  // stage this wave's 16 R1 receiver rows (8KB/wave) into LDS
  {
    const u16* r1b = R1 + (t*64 + b)*16384 + j0*256;
    #pragma unroll
    for(int it=0; it<8; ++it){
      int c = l + it*64;                 // 0..511 uint4
      int row = c >> 5, col8 = (c & 31) * 8;
      *(uint4*)&sR1[t][row][col8] = *(const uint4*)(r1b + row*256 + col8);
    }
  }
  // rel_type weights for this block's 16 receivers (per-wave t)
  #pragma unroll 1
  for(int jj=0; jj<16; ++jj){
    int j = j0 + jj, i = l;
    float v = 0.0f;
    if(i != j){ int e = i*63 + j - (j > i ? 1 : 0); v = h2f(RTc[(b*4032 + e)*4 + t]); }
    sRTa[t][jj][i] = v;
  }
  f16x8 bfr[4][8];          // whole w2T[t]: 128 VGPRs
  {
    const u16* w2t = W2T + t*16384;
    #pragma unroll
    for(int nt=0;nt<4;++nt)
      #pragma unroll
      for(int ks=0;ks<8;++ks)
        bfr[nt][ks] = *(const f16x8*)(w2t + (nt*16 + ml)*256 + ks*32 + q*8);
  }
  uint4 su[4][8];           // whole S1[t][b] A-side: 128 VGPRs, loaded ONCE
  const u16* s1b = S1 + (t*64 + b)*16384;
  #pragma unroll
  for(int mt=0;mt<4;++mt)
    #pragma unroll
    for(int ks=0;ks<8;++ks)
      su[mt][ks] = *(const uint4*)(s1b + (mt*16 + ml)*256 + ks*32 + q*8);
  f32x4 bini[4];            // bias2 pre-folded into acc init
  #pragma unroll
  for(int nt=0;nt<4;++nt){
    float bv = h2f(B2c[t*64 + nt*16 + ml]);
    bini[nt].x = bv; bini[nt].y = bv; bini[nt].z = bv; bini[nt].w = bv;
  }
  __syncthreads();          // covers sAggB zero-init (sR1/sRTa are per-wave)
  #pragma unroll 1
  for(int jp=0; jp<8; ++jp){
    const int jjA = 2*jp, jjB = 2*jp + 1;
    f32x4 accA[4][4], accB[4][4];
    #pragma unroll
    for(int mt=0;mt<4;++mt)
      #pragma unroll
      for(int nt=0;nt<4;++nt){ accA[mt][nt] = bini[nt]; accB[mt][nt] = bini[nt]; }
    #pragma unroll
    for(int ks=0;ks<8;++ks){
      const uint4 rA = *(const uint4*)&sR1[t][jjA][ks*32 + q*8];
      const uint4 rB = *(const uint4*)&sR1[t][jjB][ks*32 + q*8];
      #pragma unroll
      for(int mt=0;mt<4;++mt){
        f16x8 aA = build_frag(su[mt][ks], rA);   // relu(S1+R1) in-register
        #pragma unroll
        for(int nt=0;nt<4;++nt) accA[mt][nt] = mfma16(aA, bfr[nt][ks], accA[mt][nt]);
        f16x8 aB = build_frag(su[mt][ks], rB);
        #pragma unroll
        for(int nt=0;nt<4;++nt) accB[mt][nt] = mfma16(aB, bfr[nt][ks], accB[mt][nt]);
      }
    }
    // epilogues: relu(C) (bias pre-folded), weighted column-sum over senders
    {
      float cs[4] = {0.f,0.f,0.f,0.f};
      #pragma unroll
      for(int mt=0;mt<4;++mt){
        const f32x4 rw4 = *(const f32x4*)&sRTa[t][jjA][mt*16 + q*4];
        #pragma unroll
        for(int nt=0;nt<4;++nt)
          #pragma unroll
          for(int r=0;r<4;++r)
            cs[nt] += fmaxf(accA[mt][nt][r], 0.0f) * rw4[r];
      }
      #pragma unroll
      for(int nt=0;nt<4;++nt)
        atomicAdd(&sAggB[jjA*64 + nt*16 + ml], cs[nt]);
    }
    {
      float cs[4] = {0.f,0.f,0.f,0.f};
      #pragma unroll
      for(int mt=0;mt<4;++mt){
        const f32x4 rw4 = *(const f32x4*)&sRTa[t][jjB][mt*16 + q*4];
        #pragma unroll
        for(int nt=0;nt<4;++nt)
          #pragma unroll
          for(int r=0;r<4;++r)
            cs[nt] += fmaxf(accB[mt][nt][r], 0.0f) * rw4[r];
      }
      #pragma unroll
      for(int nt=0;nt<4;++nt)
        atomicAdd(&sAggB[jjB*64 + nt*16 + ml], cs[nt]);
    }
  }
  __syncthreads();
  float* aggb = AGG + (b*64 + j0)*64;
  #pragma unroll
  for(int it=0; it<4; ++it) aggb[it*256 + tid] = sAggB[it*256 + tid];
}

// ---------------- K3: node MLP (aug=[x,agg] -> 256 -> 256 -> 64) ----------------
__global__ __launch_bounds__(256) void k_node(const u16* __restrict__ Xc, const float* __restrict__ AGG,
    const u16* __restrict__ OW1T, const u16* __restrict__ OB1c,
    const u16* __restrict__ OW2T, const u16* __restrict__ OB2c,
    const u16* __restrict__ OW3T, const u16* __restrict__ OB3c,
    void* __restrict__ out, const int* __restrict__ flag){
  __shared__ __align__(16) u16 sA[64][136];
  __shared__ __align__(16) u16 sH[64][264];
  __shared__ __align__(16) u16 sH2[64][264];
  __shared__ __align__(16) u16 sW[64][264];
  const int tid = threadIdx.x, bb = blockIdx.x;
  const int isbf = *flag;
  {
    const uint4* src = (const uint4*)(Xc + bb*4096);
    #pragma unroll
    for(int it=0; it<2; ++it){
      int c = tid + it*256; int row = c >> 3, col = (c & 7)*8;
      *(uint4*)&sA[row][col] = src[c];
    }
    const float* ag = AGG + bb*4096;
    #pragma unroll
    for(int it=0; it<16; ++it){
      int c = tid + it*256; int row = c >> 6, col = c & 63;
      sA[row][64 + col] = f2h(ag[c]);
    }
  }
  const int wv = tid >> 6, l = tid & 63, ml = l & 15, q = l >> 4;
  const f32x4 z = {0.f,0.f,0.f,0.f};
  __syncthreads();
  for(int nc=0; nc<4; ++nc){
    #pragma unroll
    for(int it=0; it<4; ++it){
      int c = tid + it*256; int h = c >> 4, kc = (c & 15)*8;
      *(uint4*)&sW[h][kc] = *(const uint4*)(OW1T + (nc*64 + h)*128 + kc);
    }
    __syncthreads();
    f32x4 acc[4] = {z,z,z,z};
    #pragma unroll
    for(int ks=0; ks<4; ++ks){
      int kb = ks*32 + q*8;
      f16x8 bfrag = *(const f16x8*)&sW[wv*16 + ml][kb];
      #pragma unroll
      for(int mt=0;mt<4;++mt){
        f16x8 afrag = *(const f16x8*)&sA[mt*16 + ml][kb];
        acc[mt] = mfma16(afrag, bfrag, acc[mt]);
      }
    }
    const int h = nc*64 + wv*16 + ml;
    const float bias = h2f(OB1c[h]);
    #pragma unroll
    for(int mt=0;mt<4;++mt)
      #pragma unroll
      for(int r=0;r<4;++r){
        int row = mt*16 + q*4 + r;
        sH[row][h] = f2h(fmaxf(acc[mt][r] + bias, 0.0f));
      }
    __syncthreads();
  }
  for(int nc=0; nc<4; ++nc){
    #pragma unroll
    for(int it=0; it<8; ++it){
      int c = tid + it*256; int h = c >> 5, kc = (c & 31)*8;
      *(uint4*)&sW[h][kc] = *(const uint4*)(OW2T + (nc*64 + h)*256 + kc);
    }
    __syncthreads();
    f32x4 acc[4] = {z,z,z,z};
    #pragma unroll
    for(int ks=0; ks<8; ++ks){
      int kb = ks*32 + q*8;
      f16x8 bfrag = *(const f16x8*)&sW[wv*16 + ml][kb];
      #pragma unroll
      for(int mt=0;mt<4;++mt){
        f16x8 afrag = *(const f16x8*)&sH[mt*16 + ml][kb];
        acc[mt] = mfma16(afrag, bfrag, acc[mt]);
      }
    }
    const int h = nc*64 + wv*16 + ml;
    const float bias = h2f(OB2c[h]);
    #pragma unroll
    for(int mt=0;mt<4;++mt)
      #pragma unroll
      for(int r=0;r<4;++r){
        int row = mt*16 + q*4 + r;
        sH2[row][h] = f2h(fmaxf(acc[mt][r] + bias, 0.0f));
      }
    __syncthreads();
  }
  {
    #pragma unroll
    for(int it=0; it<8; ++it){
      int c = tid + it*256; int h = c >> 5, kc = (c & 31)*8;
      *(uint4*)&sW[h][kc] = *(const uint4*)(OW3T + h*256 + kc);
    }
    __syncthreads();
    f32x4 acc[4] = {z,z,z,z};
    #pragma unroll
    for(int ks=0; ks<8; ++ks){
      int kb = ks*32 + q*8;
      f16x8 bfrag = *(const f16x8*)&sW[wv*16 + ml][kb];
      #pragma unroll
      for(int mt=0;mt<4;++mt){
        f16x8 afrag = *(const f16x8*)&sH2[mt*16 + ml][kb];
        acc[mt] = mfma16(afrag, bfrag, acc[mt]);
      }
    }
    const int o = wv*16 + ml;
    const float bias = h2f(OB3c[o]);
    #pragma unroll
    for(int mt=0;mt<4;++mt)
      #pragma unroll
      for(int r=0;r<4;++r){
        int row = mt*16 + q*4 + r;
        float v = acc[mt][r] + bias;
        int idx = bb*4096 + row*64 + o;
        if(isbf) ((u16*)out)[idx] = f2bf(v);
        else     ((float*)out)[idx] = v;
      }
  }
}

extern "C" void kernel_launch(void* const* d_in, const int* in_sizes, int n_in,
                              void* d_out, int out_size, void* d_ws, size_t ws_size,
                              hipStream_t stream){
  (void)in_sizes; (void)n_in; (void)out_size; (void)ws_size;
  char* ws = (char*)d_ws;
  u16* W1T  = (u16*)(ws + OFF_W1T);
  u16* W2T  = (u16*)(ws + OFF_W2T);
  u16* OW1T = (u16*)(ws + OFF_OW1T);
  u16* OW2T = (u16*)(ws + OFF_OW2T);
  u16* OW3T = (u16*)(ws + OFF_OW3T);
  u16* B1c  = (u16*)(ws + OFF_B1);
  u16* B2c  = (u16*)(ws + OFF_B2);
  u16* OB1c = (u16*)(ws + OFF_OB1);
  u16* OB2c = (u16*)(ws + OFF_OB2);
  u16* OB3c = (u16*)(ws + OFF_OB3);
  u16* Xc   = (u16*)(ws + OFF_XC);
  u16* RTc  = (u16*)(ws + OFF_RTC);
  u16* S1   = (u16*)(ws + OFF_S1);
  u16* R1   = (u16*)(ws + OFF_R1);
  float* AGG = (float*)(ws + OFF_AGG);

  k_sniff<<<1, 64, 0, stream>>>((const u16*)d_in[0], (int*)ws);
  k_tr<<<304, 256, 0, stream>>>(d_in[4], d_in[6], d_in[8], d_in[10], d_in[12], ws);
  k_cvt2<<<5064, 256, 0, stream>>>(d_in[0], d_in[1], d_in[5], d_in[7],
                                   d_in[9], d_in[11], d_in[13], ws);
  k_s1r1<<<512, 256, 0, stream>>>(Xc, W1T, B1c, S1, R1);
  k_edge<<<256, 256, 0, stream>>>(RTc, W2T, B2c, S1, R1, AGG);
  k_node<<<64, 256, 0, stream>>>(Xc, AGG, OW1T, OB1c, OW2T, OB2c, OW3T, OB3c, d_out, (const int*)ws);
}

// Round 8
// 155.010 us; speedup vs baseline: 1.7453x; 1.1346x over previous
//
#include <hip/hip_runtime.h>

typedef unsigned short u16;
typedef __attribute__((ext_vector_type(8))) _Float16 f16x8;
typedef __attribute__((ext_vector_type(2))) _Float16 f16x2;
typedef __attribute__((ext_vector_type(4))) float f32x4;

#define DEV static __device__ __forceinline__

DEV float bf2f(u16 h){ unsigned u = ((unsigned)h) << 16; return __builtin_bit_cast(float, u); }
DEV u16 f2bf(float f){ unsigned u = __builtin_bit_cast(unsigned, f); u += 0x7FFFu + ((u >> 16) & 1u); return (u16)(u >> 16); }
DEV u16 f2h(float f){ _Float16 h = (_Float16)f; return __builtin_bit_cast(u16, h); }
DEV float h2f(u16 h){ return (float)__builtin_bit_cast(_Float16, h); }

DEV f32x4 mfma16(f16x8 a, f16x8 b, f32x4 c){
  return __builtin_amdgcn_mfma_f32_16x16x32_f16(a, b, c, 0, 0, 0);
}

// relu(S1+R1) on 8 packed halves: 4x v_pk_add_f16 + 4x v_pk_max_f16.
DEV f16x8 build_frag(uint4 s, uint4 r){
  f16x8 a = __builtin_bit_cast(f16x8, s);
  f16x8 b = __builtin_bit_cast(f16x8, r);
  f16x8 v = a + b;
  const f16x8 z = {0,0,0,0,0,0,0,0};
  return __builtin_elementwise_max(v, z);
}

// Per-kernel dtype sniff (replaces the k_sniff kernel + ws flag round-trip):
// one L2-hot 256B read + wave ballot, wave-uniform result, ~300cy.
DEV int sniff_isbf(const void* x){
  int l = threadIdx.x & 63;
  u16 u = ((const u16*)x)[2 * l];
  int e = (u >> 7) & 0xFF;
  int ok = (e >= 103 && e <= 143) ? 1 : 0;
  unsigned long long m = __ballot(ok);
  return (__builtin_popcountll(m) >= 40) ? 1 : 0;  // 1 = bf16 I/O
}

DEV float ldin(const void* p, int i, int isbf){
  return isbf ? bf2f(((const u16*)p)[i]) : ((const float*)p)[i];
}

DEV unsigned pk2(float a, float b){ return (unsigned)f2h(a) | ((unsigned)f2h(b) << 16); }
DEV unsigned pkbf(unsigned w){
  float lo = bf2f((u16)(w & 0xffff)), hi = bf2f((u16)(w >> 16));
  return pk2(lo, hi);
}
// load 8 source elements (group index g of 8) as 8 packed f16
DEV uint4 ld8f16(const void* p, int g, int isbf){
  uint4 r;
  if(isbf){
    uint4 v = ((const uint4*)p)[g];
    r.x = pkbf(v.x); r.y = pkbf(v.y); r.z = pkbf(v.z); r.w = pkbf(v.w);
  } else {
    float4 a = ((const float4*)p)[2*g], b4 = ((const float4*)p)[2*g + 1];
    r.x = pk2(a.x, a.y); r.y = pk2(a.z, a.w); r.z = pk2(b4.x, b4.y); r.w = pk2(b4.z, b4.w);
  }
  return r;
}

// Sizes: B=64, N=64, F=64, H=256, O=64, T=4, E=4032
// ws layout (bytes): W1T@256 | W2T@262400 | OW1T@393472 | OW2T@459008
//  | OW3T@590080 | S1@3215360 | R1@11603968 | AGG(f32)@19992576
#define OFF_W1T  256
#define OFF_W2T  262400
#define OFF_OW1T 393472
#define OFF_OW2T 459008
#define OFF_OW3T 590080
#define OFF_S1   3215360
#define OFF_R1   11603968
#define OFF_AGG  19992576

// ---------------- K0: tiled transpose+convert for the 5 weight matrices ----------------
// src [G][R][C] -> dst [G][C][R], 32x32 LDS tiles, coalesced read+write.
__global__ __launch_bounds__(256) void k_tr(const void* __restrict__ x, const void* __restrict__ w1,
    const void* __restrict__ w2, const void* __restrict__ ow1, const void* __restrict__ ow2,
    const void* __restrict__ ow3, char* __restrict__ ws){
  const int isbf = sniff_isbf(x);
  __shared__ float tile[32][33];
  int bid = blockIdx.x, tid = threadIdx.x;
  const void* src; u16* dst; int R, C, off, r0, c0;
  if(bid < 128){ int g = bid >> 5, tt = bid & 31;
    src = w1; dst = (u16*)(ws + OFF_W1T); R = 128; C = 256; off = g * 32768;
    r0 = (tt >> 3) << 5; c0 = (tt & 7) << 5;
  } else if(bid < 192){ int bb = bid - 128; int g = bb >> 4, tt = bb & 15;
    src = w2; dst = (u16*)(ws + OFF_W2T); R = 256; C = 64; off = g * 16384;
    r0 = (tt >> 1) << 5; c0 = (tt & 1) << 5;
  } else if(bid < 224){ int bb = bid - 192;
    src = ow1; dst = (u16*)(ws + OFF_OW1T); R = 128; C = 256; off = 0;
    r0 = (bb >> 3) << 5; c0 = (bb & 7) << 5;
  } else if(bid < 288){ int bb = bid - 224;
    src = ow2; dst = (u16*)(ws + OFF_OW2T); R = 256; C = 256; off = 0;
    r0 = (bb >> 3) << 5; c0 = (bb & 7) << 5;
  } else { int bb = bid - 288;
    src = ow3; dst = (u16*)(ws + OFF_OW3T); R = 256; C = 64; off = 0;
    r0 = (bb >> 1) << 5; c0 = (bb & 1) << 5;
  }
  int tx = tid & 31, ty = tid >> 5;
  #pragma unroll
  for(int p = 0; p < 4; ++p){
    int r = ty + p * 8;
    tile[r][tx] = ldin(src, off + (r0 + r) * C + c0 + tx, isbf);
  }
  __syncthreads();
  #pragma unroll
  for(int p = 0; p < 4; ++p){
    int c = ty + p * 8;
    dst[off + (c0 + c) * R + r0 + tx] = f2h(tile[tx][c]);
  }
}

// ---------------- K1: S1/R1 = x @ w1-half (+b1 on receiver half) ----------------
// x converted inline during sX staging (k_cvt2 eliminated); b1 read raw.
__global__ __launch_bounds__(256) void k_s1r1(const void* __restrict__ x, const u16* __restrict__ W1T,
    const void* __restrict__ b1, u16* __restrict__ S1, u16* __restrict__ R1){
  __shared__ __align__(16) u16 sX[64][72];
  __shared__ __align__(16) u16 sW[256][72];
  const int tid = threadIdx.x, bid = blockIdx.x;
  const int b = bid & 63, th = bid >> 6, t = th >> 1, half = th & 1;
  const int isbf = sniff_isbf(x);
  {
    #pragma unroll
    for(int it=0; it<2; ++it){
      int c = tid + it*256; int row = c >> 3, col = (c & 7) * 8;
      *(uint4*)&sX[row][col] = ld8f16(x, b*512 + c, isbf);
    }
    const u16* base = W1T + t*32768 + half*64;
    #pragma unroll
    for(int it=0; it<8; ++it){
      int c = tid + it*256; int h = c >> 3, kc = (c & 7) * 8;
      *(uint4*)&sW[h][kc] = *(const uint4*)(base + h*128 + kc);
    }
  }
  __syncthreads();
  const int wv = tid >> 6, l = tid & 63, ml = l & 15, q = l >> 4;
  const f32x4 z = {0.f,0.f,0.f,0.f};
  f32x4 acc[4][4];
  #pragma unroll
  for(int mt=0;mt<4;++mt){ acc[mt][0]=z; acc[mt][1]=z; acc[mt][2]=z; acc[mt][3]=z; }
  #pragma unroll
  for(int ks=0; ks<2; ++ks){
    const int kb = ks*32 + q*8;
    f16x8 af[4], bff[4];
    #pragma unroll
    for(int mt=0;mt<4;++mt) af[mt] = *(const f16x8*)&sX[mt*16 + ml][kb];
    #pragma unroll
    for(int nt=0;nt<4;++nt) bff[nt] = *(const f16x8*)&sW[wv*64 + nt*16 + ml][kb];
    #pragma unroll
    for(int mt=0;mt<4;++mt)
      #pragma unroll
      for(int nt=0;nt<4;++nt)
        acc[mt][nt] = mfma16(af[mt], bff[nt], acc[mt][nt]);
  }
  u16* dst = (half ? R1 : S1) + (t*64 + b)*16384;
  #pragma unroll
  for(int nt=0;nt<4;++nt){
    const int h = wv*64 + nt*16 + ml;
    const float bias = half ? ldin(b1, t*256 + h, isbf) : 0.0f;
    #pragma unroll
    for(int mt=0;mt<4;++mt)
      #pragma unroll
      for(int r=0;r<4;++r){
        int irow = mt*16 + q*4 + r;
        dst[irow*256 + h] = f2h(acc[mt][nt][r] + bias);
      }
  }
}

// ---------------- K2: per-edge layer-2 + weighted receiver aggregation ----------------
// EXACT R3 structure (best measured: 55.9us; R6 more-waves and R7 more-ILP
// both regressed -> per-wave latency-bound local optimum). Only changes:
// rel_type and b2 read RAW (inline convert; k_cvt2 eliminated) + self-sniff.
// grid 256: block = (b, group of 16 receivers). wave = edge type t.
__global__ __launch_bounds__(256, 1) void k_edge(const void* __restrict__ x, const void* __restrict__ rt,
    const u16* __restrict__ W2T, const void* __restrict__ b2,
    const u16* __restrict__ S1, const u16* __restrict__ R1, float* __restrict__ AGG){
  __shared__ float sRTa[4][16][64];
  __shared__ float sAggB[1024];
  const int tid = threadIdx.x;
  const int t = tid >> 6, l = tid & 63, ml = l & 15, q = l >> 4;
  const int b = blockIdx.x >> 2, j0 = (blockIdx.x & 3) * 16;
  const int isbf = sniff_isbf(x);
  #pragma unroll
  for(int it=0; it<4; ++it) sAggB[it*256 + tid] = 0.0f;
  // this block's 16 receivers' rel_type weights (per-wave, same-wave use)
  #pragma unroll 1
  for(int jj=0; jj<16; ++jj){
    int j = j0 + jj, i = l;
    float v = 0.0f;
    if(i != j){ int e = i*63 + j - (j > i ? 1 : 0); v = ldin(rt, (b*4032 + e)*4 + t, isbf); }
    sRTa[t][jj][i] = v;
  }
  __syncthreads();          // covers sAggB zero-init
  f16x8 bfr[4][8];          // whole w2T[t]: 128 VGPRs
  {
    const u16* w2t = W2T + t*16384;
    #pragma unroll
    for(int nt=0;nt<4;++nt)
      #pragma unroll
      for(int ks=0;ks<8;++ks)
        bfr[nt][ks] = *(const f16x8*)(w2t + (nt*16 + ml)*256 + ks*32 + q*8);
  }
  uint4 su[4][8];           // whole S1[t][b] A-side: 128 VGPRs, loaded ONCE
  const u16* s1b = S1 + (t*64 + b)*16384;
  #pragma unroll
  for(int mt=0;mt<4;++mt)
    #pragma unroll
    for(int ks=0;ks<8;++ks)
      su[mt][ks] = *(const uint4*)(s1b + (mt*16 + ml)*256 + ks*32 + q*8);
  f32x4 bini[4];            // bias2 pre-folded into acc init
  #pragma unroll
  for(int nt=0;nt<4;++nt){
    float bv = ldin(b2, t*64 + nt*16 + ml, isbf);
    bini[nt].x = bv; bini[nt].y = bv; bini[nt].z = bv; bini[nt].w = bv;
  }
  const u16* r1b = R1 + (t*64 + b)*16384;
  uint4 ru[8], run[8];
  #pragma unroll
  for(int ks=0;ks<8;++ks) ru[ks] = *(const uint4*)(r1b + j0*256 + ks*32 + q*8);
  #pragma unroll 1
  for(int jj=0; jj<16; ++jj){
    // hoisted LDS reads: this jj's 16 rel_type weights (4 rows per mt), b128 each
    f32x4 rw4[4];
    #pragma unroll
    for(int mt=0;mt<4;++mt) rw4[mt] = *(const f32x4*)&sRTa[t][jj][mt*16 + q*4];
    if(jj < 15){            // prefetch next receiver row while MFMAs run
      const u16* r1n = r1b + (j0 + jj + 1)*256;
      #pragma unroll
      for(int ks=0;ks<8;++ks) run[ks] = *(const uint4*)(r1n + ks*32 + q*8);
    }
    f32x4 acc[4][4];
    #pragma unroll
    for(int mt=0;mt<4;++mt){
      acc[mt][0]=bini[0]; acc[mt][1]=bini[1]; acc[mt][2]=bini[2]; acc[mt][3]=bini[3];
    }
    #pragma unroll
    for(int ks=0;ks<8;++ks){
      #pragma unroll
      for(int mt=0;mt<4;++mt){
        f16x8 af = build_frag(su[mt][ks], ru[ks]);   // relu(S1+R1) in-register
        #pragma unroll
        for(int nt=0;nt<4;++nt) acc[mt][nt] = mfma16(af, bfr[nt][ks], acc[mt][nt]);
      }
    }
    // epilogue: relu(C) (bias pre-folded), weighted column-sum over sender rows i
    float cs[4] = {0.f,0.f,0.f,0.f};
    #pragma unroll
    for(int mt=0;mt<4;++mt)
      #pragma unroll
      for(int nt=0;nt<4;++nt)
        #pragma unroll
        for(int r=0;r<4;++r)
          cs[nt] += fmaxf(acc[mt][nt][r], 0.0f) * rw4[mt][r];
    // all-lane fire-and-forget LDS atomic (4-way same-address conflict is
    // ~16 LDS slots vs ~1400cy of dependent shfl latency it replaces)
    #pragma unroll
    for(int nt=0;nt<4;++nt)
      atomicAdd(&sAggB[jj*64 + nt*16 + ml], cs[nt]);
    #pragma unroll
    for(int ks=0;ks<8;++ks) ru[ks] = run[ks];
  }
  __syncthreads();
  float* aggb = AGG + (b*64 + j0)*64;
  #pragma unroll
  for(int it=0; it<4; ++it) aggb[it*256 + tid] = sAggB[it*256 + tid];
}

// ---------------- K3: node MLP (aug=[x,agg] -> 256 -> 256 -> 64) ----------------
// R8: rows are independent through the whole MLP -> split 4-way: 256 blocks
// (bb, row-group of 16) instead of 64, quartering the serial critical path
// and using all CUs. x and ob* converted/read inline (k_cvt2 eliminated).
__global__ __launch_bounds__(256) void k_node(const void* __restrict__ x, const float* __restrict__ AGG,
    const u16* __restrict__ OW1T, const void* __restrict__ ob1,
    const u16* __restrict__ OW2T, const void* __restrict__ ob2,
    const u16* __restrict__ OW3T, const void* __restrict__ ob3,
    void* __restrict__ out){
  __shared__ __align__(16) u16 sA[16][136];
  __shared__ __align__(16) u16 sH[16][264];
  __shared__ __align__(16) u16 sH2[16][264];
  __shared__ __align__(16) u16 sW[64][264];
  const int tid = threadIdx.x;
  const int bb = blockIdx.x >> 2, rg = blockIdx.x & 3;
  const int isbf = sniff_isbf(x);
  {
    if(tid < 128){           // x part: 16 rows x 64 cols = 128 groups of 8
      int row = tid >> 3, gc = tid & 7;
      *(uint4*)&sA[row][gc*8] = ld8f16(x, bb*512 + (rg*16 + row)*8 + gc, isbf);
    }
    const float* ag = AGG + bb*4096;
    #pragma unroll
    for(int it=0; it<4; ++it){
      int c = tid + it*256; int row = c >> 6, col = c & 63;
      sA[row][64 + col] = f2h(ag[(rg*16 + row)*64 + col]);
    }
  }
  const int wv = tid >> 6, l = tid & 63, ml = l & 15, q = l >> 4;
  const f32x4 z = {0.f,0.f,0.f,0.f};
  __syncthreads();
  for(int nc=0; nc<4; ++nc){
    #pragma unroll
    for(int it=0; it<4; ++it){
      int c = tid + it*256; int h = c >> 4, kc = (c & 15)*8;
      *(uint4*)&sW[h][kc] = *(const uint4*)(OW1T + (nc*64 + h)*128 + kc);
    }
    __syncthreads();
    f32x4 acc = z;
    #pragma unroll
    for(int ks=0; ks<4; ++ks){
      int kb = ks*32 + q*8;
      f16x8 bfrag = *(const f16x8*)&sW[wv*16 + ml][kb];
      f16x8 afrag = *(const f16x8*)&sA[ml][kb];
      acc = mfma16(afrag, bfrag, acc);
    }
    const int h = nc*64 + wv*16 + ml;
    const float bias = ldin(ob1, h, isbf);
    #pragma unroll
    for(int r=0;r<4;++r)
      sH[q*4 + r][h] = f2h(fmaxf(acc[r] + bias, 0.0f));
    __syncthreads();
  }
  for(int nc=0; nc<4; ++nc){
    #pragma unroll
    for(int it=0; it<8; ++it){
      int c = tid + it*256; int h = c >> 5, kc = (c & 31)*8;
      *(uint4*)&sW[h][kc] = *(const uint4*)(OW2T + (nc*64 + h)*256 + kc);
    }
    __syncthreads();
    f32x4 acc = z;
    #pragma unroll
    for(int ks=0; ks<8; ++ks){
      int kb = ks*32 + q*8;
      f16x8 bfrag = *(const f16x8*)&sW[wv*16 + ml][kb];
      f16x8 afrag = *(const f16x8*)&sH[ml][kb];
      acc = mfma16(afrag, bfrag, acc);
    }
    const int h = nc*64 + wv*16 + ml;
    const float bias = ldin(ob2, h, isbf);
    #pragma unroll
    for(int r=0;r<4;++r)
      sH2[q*4 + r][h] = f2h(fmaxf(acc[r] + bias, 0.0f));
    __syncthreads();
  }
  {
    #pragma unroll
    for(int it=0; it<8; ++it){
      int c = tid + it*256; int h = c >> 5, kc = (c & 31)*8;
      *(uint4*)&sW[h][kc] = *(const uint4*)(OW3T + h*256 + kc);
    }
    __syncthreads();
    f32x4 acc = z;
    #pragma unroll
    for(int ks=0; ks<8; ++ks){
      int kb = ks*32 + q*8;
      f16x8 bfrag = *(const f16x8*)&sW[wv*16 + ml][kb];
      f16x8 afrag = *(const f16x8*)&sH2[ml][kb];
      acc = mfma16(afrag, bfrag, acc);
    }
    const int o = wv*16 + ml;
    const float bias = ldin(ob3, o, isbf);
    #pragma unroll
    for(int r=0;r<4;++r){
      int row = rg*16 + q*4 + r;
      float v = acc[r] + bias;
      int idx = bb*4096 + row*64 + o;
      if(isbf) ((u16*)out)[idx] = f2bf(v);
      else     ((float*)out)[idx] = v;
    }
  }
}

extern "C" void kernel_launch(void* const* d_in, const int* in_sizes, int n_in,
                              void* d_out, int out_size, void* d_ws, size_t ws_size,
                              hipStream_t stream){
  (void)in_sizes; (void)n_in; (void)out_size; (void)ws_size;
  char* ws = (char*)d_ws;
  u16* W1T  = (u16*)(ws + OFF_W1T);
  u16* W2T  = (u16*)(ws + OFF_W2T);
  u16* OW1T = (u16*)(ws + OFF_OW1T);
  u16* OW2T = (u16*)(ws + OFF_OW2T);
  u16* OW3T = (u16*)(ws + OFF_OW3T);
  u16* S1   = (u16*)(ws + OFF_S1);
  u16* R1   = (u16*)(ws + OFF_R1);
  float* AGG = (float*)(ws + OFF_AGG);

  // 4 kernels (was 6): k_sniff folded into each kernel (per-wave ballot);
  // k_cvt2 folded into consumers (inline dtype conversion during staging).
  k_tr<<<304, 256, 0, stream>>>(d_in[0], d_in[4], d_in[6], d_in[8], d_in[10], d_in[12], ws);
  k_s1r1<<<512, 256, 0, stream>>>(d_in[0], W1T, d_in[5], S1, R1);
  k_edge<<<256, 256, 0, stream>>>(d_in[0], d_in[1], W2T, d_in[7], S1, R1, AGG);
  k_node<<<256, 256, 0, stream>>>(d_in[0], AGG, OW1T, d_in[9], OW2T, d_in[11], OW3T, d_in[13], d_out);
}